// Round 1
// baseline (872.373 us; speedup 1.0000x reference)
//
#include <hip/hip_runtime.h>
#include <stdint.h>

#define T_TOK 8192
#define DDIM 1024
#define EEXP 8
#define FDIM 2048

typedef float f32x4 __attribute__((ext_vector_type(4)));
typedef __bf16 bf16x8 __attribute__((ext_vector_type(8)));
typedef unsigned short us8 __attribute__((ext_vector_type(8)));

__device__ __forceinline__ unsigned short f2bf(float f) {
  union { float f; unsigned int u; } v; v.f = f;
  unsigned int r = (v.u + 0x7fffu + ((v.u >> 16) & 1u)) >> 16;
  return (unsigned short)r;
}

__device__ __forceinline__ void async_cp16(const void* g, void* l) {
  __builtin_amdgcn_global_load_lds(
      (const __attribute__((address_space(1))) unsigned int*)g,
      (__attribute__((address_space(3))) unsigned int*)l, 16, 0, 0);
}

// ---------------- cast x fp32 -> bf16 ----------------
__global__ __launch_bounds__(256) void castx_kernel(const float* __restrict__ in,
                                                    unsigned short* __restrict__ out,
                                                    int n4) {
  int i = blockIdx.x * 256 + threadIdx.x;
  if (i >= n4) return;
  float4 v = ((const float4*)in)[i];
  ushort4 o;
  o.x = f2bf(v.x); o.y = f2bf(v.y); o.z = f2bf(v.z); o.w = f2bf(v.w);
  ((ushort4*)out)[i] = o;
}

// ---------------- merged vectorized transpose-cast of w1/w3/w2 ----------------
// z 0..7 -> w1 [e][1024][2048] -> w1t [e][2048][1024]
// z 8..15 -> w3 same shapes
// z 16..23 -> w2 [e][2048][1024] -> w2t [e][1024][2048]
// Global: float4 reads (16B/lane), ushort8 writes (16B/lane).
// LDS tile[64][65]: phase1 scalar writes bank = (r + 4c + k) mod 32 (2-way max);
// phase2 scalar reads bank = (8*(t&7) + j + (t>>3)) mod 32 (2-way max) -- free per m136.
__global__ __launch_bounds__(256) void transpose_cast3_kernel(
    const float* __restrict__ w1, const float* __restrict__ w3, const float* __restrict__ w2,
    unsigned short* __restrict__ w1t, unsigned short* __restrict__ w3t,
    unsigned short* __restrict__ w2t) {
  __shared__ float tile[64][65];
  const int z = blockIdx.z;
  const float* in;
  unsigned short* out;
  int R, C;
  if (z < 16) {
    R = DDIM; C = FDIM;
    const float* s = (z < 8) ? w1 : w3;
    unsigned short* o = (z < 8) ? w1t : w3t;
    in = s + (size_t)(z & 7) * R * C;
    out = o + (size_t)(z & 7) * R * C;
  } else {
    R = FDIM; C = DDIM;
    in = w2 + (size_t)(z & 7) * R * C;
    out = w2t + (size_t)(z & 7) * R * C;
  }
  const int c0 = blockIdx.x * 64;
  const int r0 = blockIdx.y * 64;
  if (c0 >= C || r0 >= R) return;
  const int t = threadIdx.x;
  const int pr = t >> 4;          // 0..15
  const int pc = (t & 15) * 4;    // 0..60
#pragma unroll
  for (int i = 0; i < 4; i++) {
    float4 v = *(const float4*)&in[(size_t)(r0 + pr + i * 16) * C + c0 + pc];
    tile[pr + i * 16][pc + 0] = v.x;
    tile[pr + i * 16][pc + 1] = v.y;
    tile[pr + i * 16][pc + 2] = v.z;
    tile[pr + i * 16][pc + 3] = v.w;
  }
  __syncthreads();
  const int qr = (t & 7) * 8;     // 0..56
  const int qc = t >> 3;          // 0..31
#pragma unroll
  for (int i = 0; i < 2; i++) {
    int cc = qc + i * 32;
    us8 o;
#pragma unroll
    for (int j = 0; j < 8; j++) o[j] = f2bf(tile[qr + j][cc]);
    *(us8*)&out[(size_t)(c0 + cc) * R + r0 + qr] = o;
  }
}

// ---------------- gating: wave per token ----------------
// hdr layout (ints): [0..7]=cnt, [8..15]=fill, [16..24]=offs
__global__ __launch_bounds__(256) void gate_kernel(const float* __restrict__ x,
                                                   const float* __restrict__ wg,
                                                   int* __restrict__ sel,
                                                   float* __restrict__ prb,
                                                   int* __restrict__ hdr) {
  __shared__ float wgs[8 * 1024];  // transposed [e][d]
  int tid = threadIdx.x;
  for (int i = tid; i < 8192; i += 256) {
    int d = i >> 3, e = i & 7;
    wgs[e * 1024 + d] = wg[i];
  }
  __syncthreads();
  int lane = tid & 63;
  int t = blockIdx.x * 4 + (tid >> 6);
  const float* xr = x + (size_t)t * 1024;
  float acc[8] = {0.f, 0.f, 0.f, 0.f, 0.f, 0.f, 0.f, 0.f};
  for (int d = lane; d < 1024; d += 64) {
    float xv = xr[d];
#pragma unroll
    for (int e = 0; e < 8; e++) acc[e] += xv * wgs[e * 1024 + d];
  }
#pragma unroll
  for (int e = 0; e < 8; e++) {
    acc[e] += __shfl_xor(acc[e], 32);
    acc[e] += __shfl_xor(acc[e], 16);
    acc[e] += __shfl_xor(acc[e], 8);
    acc[e] += __shfl_xor(acc[e], 4);
    acc[e] += __shfl_xor(acc[e], 2);
    acc[e] += __shfl_xor(acc[e], 1);
  }
  if (lane == 0) {
    int i0 = 0; float v0 = acc[0];
#pragma unroll
    for (int e = 1; e < 8; e++) if (acc[e] > v0) { v0 = acc[e]; i0 = e; }
    int i1 = -1; float v1 = -1e30f;
#pragma unroll
    for (int e = 0; e < 8; e++) if (e != i0 && acc[e] > v1) { v1 = acc[e]; i1 = e; }
    float ex = __expf(v1 - v0);
    float inv = 1.0f / (1.0f + ex);
    sel[t * 2] = i0; sel[t * 2 + 1] = i1;
    prb[t * 2] = inv; prb[t * 2 + 1] = ex * inv;
    atomicAdd(&hdr[i0], 1);
    atomicAdd(&hdr[i1], 1);
  }
}

__global__ void scan_kernel(int* hdr) {
  if (threadIdx.x == 0 && blockIdx.x == 0) {
    int s = 0;
    for (int e = 0; e < 8; e++) { hdr[16 + e] = s; s += hdr[e]; }
    hdr[24] = s;
  }
}

__global__ __launch_bounds__(256) void build_kernel(const int* __restrict__ sel,
                                                    const float* __restrict__ prb,
                                                    int* __restrict__ hdr,
                                                    int* __restrict__ rows,
                                                    float* __restrict__ prbs) {
  int i = blockIdx.x * 256 + threadIdx.x;
  if (i >= T_TOK * 2) return;
  int e = sel[i];
  int pos = hdr[16 + e] + atomicAdd(&hdr[8 + e], 1);
  rows[pos] = i >> 1;
  prbs[pos] = prb[i];
}

// LDS bank swizzle: physical k-group = logical ^ ((row>>1)&3).
// Load side: thread tid stages phys slot (row=tid>>2, p=tid&3) from logical
// k-offset ((tid&3)^((tid>>3)&3))*8. Read side: q8s below. 16 lanes of a frag
// then span 8 distinct 4-bank groups at 2-way aliasing (free) instead of 8-way.

// ---------------- GEMM1: h = silu(x@w1)*(x@w3) ------------------------------
// Block 128(M) x 64(N), 4 waves 2x2, wave 64x32 dual-B. acc 64 AGPR, 3 w/SIMD.
__global__ __launch_bounds__(256, 3) void gemm1_kernel(
    const unsigned short* __restrict__ xb,   // [T][D] bf16
    const unsigned short* __restrict__ w1t,  // [E][F][D] bf16
    const unsigned short* __restrict__ w3t,  // [E][F][D] bf16
    const int* __restrict__ rows,            // slot -> token
    const int* __restrict__ hdr,
    unsigned short* __restrict__ h)          // [T*2][F] bf16 (slot space)
{
  const int e = blockIdx.z;
  const int count = hdr[e];
  const int m0 = blockIdx.y * 128;
  if (m0 >= count) return;
  const int n0 = blockIdx.x * 64;
  const int sbase = hdr[16 + e];

  __shared__ unsigned short As[2][4096];   // 128 x 32
  __shared__ unsigned short B1s[2][2048];  // 64 x 32
  __shared__ unsigned short B3s[2][2048];  // 64 x 32

  const int tid = threadIdx.x;
  const int kcol = (((tid & 3) ^ ((tid >> 3) & 3))) * 8;  // swizzled fetch col
  const int r0 = tid >> 2;                 // 0..63
  int mr0 = m0 + r0;      if (mr0 > count - 1) mr0 = count - 1;
  int mr1 = m0 + r0 + 64; if (mr1 > count - 1) mr1 = count - 1;
  const int tok0 = rows[sbase + mr0];
  const int tok1 = rows[sbase + mr1];
  const unsigned short* pA0 = xb + (size_t)tok0 * DDIM + kcol;
  const unsigned short* pA1 = xb + (size_t)tok1 * DDIM + kcol;
  const unsigned short* pB1 = w1t + ((size_t)e * FDIM + n0 + r0) * DDIM + kcol;
  const unsigned short* pB3 = w3t + ((size_t)e * FDIM + n0 + r0) * DDIM + kcol;
  const int l0 = tid * 8;

  const int wv = tid >> 6;
  const int wr = (wv >> 1) * 64;           // 0 / 64
  const int wc = (wv & 1) * 32;            // 0 / 32
  const int lane = tid & 63;
  const int q8s = (((lane >> 4) ^ ((lane >> 1) & 3))) * 8;  // swizzled read col
  const int lm = lane & 15;

  f32x4 acc1[4][2], acc3[4][2];
#pragma unroll
  for (int i = 0; i < 4; i++)
#pragma unroll
    for (int j = 0; j < 2; j++) {
      acc1[i][j] = f32x4{0.f, 0.f, 0.f, 0.f};
      acc3[i][j] = f32x4{0.f, 0.f, 0.f, 0.f};
    }

  async_cp16(pA0, &As[0][l0]);
  async_cp16(pA1, &As[0][l0 + 2048]);
  async_cp16(pB1, &B1s[0][l0]);
  async_cp16(pB3, &B3s[0][l0]);

  for (int kt = 0; kt < DDIM; kt += 32) {
    const int cur = (kt >> 5) & 1;
    __syncthreads();
    if (kt + 32 < DDIM) {
      const int nxt = cur ^ 1;
      async_cp16(pA0 + kt + 32, &As[nxt][l0]);
      async_cp16(pA1 + kt + 32, &As[nxt][l0 + 2048]);
      async_cp16(pB1 + kt + 32, &B1s[nxt][l0]);
      async_cp16(pB3 + kt + 32, &B3s[nxt][l0]);
    }

    bf16x8 a[4], b1[2], b3[2];
#pragma unroll
    for (int i = 0; i < 4; i++)
      a[i] = *(const bf16x8*)&As[cur][(wr + i * 16 + lm) * 32 + q8s];
#pragma unroll
    for (int j = 0; j < 2; j++) {
      b1[j] = *(const bf16x8*)&B1s[cur][(wc + j * 16 + lm) * 32 + q8s];
      b3[j] = *(const bf16x8*)&B3s[cur][(wc + j * 16 + lm) * 32 + q8s];
    }
#pragma unroll
    for (int i = 0; i < 4; i++)
#pragma unroll
      for (int j = 0; j < 2; j++) {
        acc1[i][j] = __builtin_amdgcn_mfma_f32_16x16x32_bf16(a[i], b1[j], acc1[i][j], 0, 0, 0);
        acc3[i][j] = __builtin_amdgcn_mfma_f32_16x16x32_bf16(a[i], b3[j], acc3[i][j], 0, 0, 0);
      }
  }

#pragma unroll
  for (int i = 0; i < 4; i++) {
#pragma unroll
    for (int r = 0; r < 4; r++) {
      int ml = wr + i * 16 + (lane >> 4) * 4 + r;
      int mg = m0 + ml;
      if (mg < count) {
        unsigned short* hp = h + (size_t)(sbase + mg) * FDIM + n0 + wc + lm;
#pragma unroll
        for (int j = 0; j < 2; j++) {
          float v1 = acc1[i][j][r];
          float v3 = acc3[i][j][r];
          float hv = (v1 / (1.0f + __expf(-v1))) * v3;
          hp[j * 16] = f2bf(hv);
        }
      }
    }
  }
}

// ---------------- GEMM2: out[tok] += prbs[slot] * (h[slot] @ w2) -------------
// Block 128(M) x 128(N), 4 waves 2x2, wave 64x64. acc 64 AGPR, 3 w/SIMD.
// Epilogue: prb-scaled HW fp32 atomics straight into out (zero-initialized).
// Each out element receives exactly 2 commutative adds -> deterministic.
__global__ __launch_bounds__(256, 3) void gemm2_kernel(
    const unsigned short* __restrict__ h,    // [T*2][F] bf16
    const unsigned short* __restrict__ w2t,  // [E][D][F] bf16
    const int* __restrict__ rows,            // slot -> token
    const float* __restrict__ prbs,          // slot -> prob
    const int* __restrict__ hdr,
    float* __restrict__ out)                 // [T][D] fp32
{
  const int e = blockIdx.z;
  const int count = hdr[e];
  const int m0 = blockIdx.y * 128;
  if (m0 >= count) return;
  const int n0 = blockIdx.x * 128;
  const int sbase = hdr[16 + e];

  __shared__ unsigned short Ahs[2][4096];  // 128 x 32
  __shared__ unsigned short Bs[2][4096];   // 128 x 32

  const int tid = threadIdx.x;
  const int kcol = (((tid & 3) ^ ((tid >> 3) & 3))) * 8;
  const int r0 = tid >> 2;
  int mr0 = m0 + r0;      if (mr0 > count - 1) mr0 = count - 1;
  int mr1 = m0 + r0 + 64; if (mr1 > count - 1) mr1 = count - 1;
  const unsigned short* pA0 = h + (size_t)(sbase + mr0) * FDIM + kcol;
  const unsigned short* pA1 = h + (size_t)(sbase + mr1) * FDIM + kcol;
  const unsigned short* pB0 = w2t + ((size_t)e * DDIM + n0 + r0) * FDIM + kcol;
  const unsigned short* pB1 = w2t + ((size_t)e * DDIM + n0 + r0 + 64) * FDIM + kcol;
  const int l0 = tid * 8;

  const int wv = tid >> 6;
  const int wr = (wv >> 1) * 64;
  const int wc = (wv & 1) * 64;
  const int lane = tid & 63;
  const int q8s = (((lane >> 4) ^ ((lane >> 1) & 3))) * 8;
  const int lm = lane & 15;

  f32x4 acc[4][4];
#pragma unroll
  for (int i = 0; i < 4; i++)
#pragma unroll
    for (int j = 0; j < 4; j++) acc[i][j] = f32x4{0.f, 0.f, 0.f, 0.f};

  async_cp16(pA0, &Ahs[0][l0]);
  async_cp16(pA1, &Ahs[0][l0 + 2048]);
  async_cp16(pB0, &Bs[0][l0]);
  async_cp16(pB1, &Bs[0][l0 + 2048]);

  for (int kt = 0; kt < FDIM; kt += 32) {
    const int cur = (kt >> 5) & 1;
    __syncthreads();
    if (kt + 32 < FDIM) {
      const int nxt = cur ^ 1;
      async_cp16(pA0 + kt + 32, &Ahs[nxt][l0]);
      async_cp16(pA1 + kt + 32, &Ahs[nxt][l0 + 2048]);
      async_cp16(pB0 + kt + 32, &Bs[nxt][l0]);
      async_cp16(pB1 + kt + 32, &Bs[nxt][l0 + 2048]);
    }

    bf16x8 a[4], b[4];
#pragma unroll
    for (int i = 0; i < 4; i++)
      a[i] = *(const bf16x8*)&Ahs[cur][(wr + i * 16 + lm) * 32 + q8s];
#pragma unroll
    for (int j = 0; j < 4; j++)
      b[j] = *(const bf16x8*)&Bs[cur][(wc + j * 16 + lm) * 32 + q8s];
#pragma unroll
    for (int i = 0; i < 4; i++)
#pragma unroll
      for (int j = 0; j < 4; j++)
        acc[i][j] = __builtin_amdgcn_mfma_f32_16x16x32_bf16(a[i], b[j], acc[i][j], 0, 0, 0);
  }

#pragma unroll
  for (int i = 0; i < 4; i++) {
#pragma unroll
    for (int r = 0; r < 4; r++) {
      int ml = wr + i * 16 + (lane >> 4) * 4 + r;
      int mg = m0 + ml;
      if (mg < count) {
        int tok = rows[sbase + mg];
        float p = prbs[sbase + mg];
        float* op = out + (size_t)tok * DDIM + n0 + wc + lm;
#pragma unroll
        for (int j = 0; j < 4; j++) unsafeAtomicAdd(&op[j * 16], p * acc[i][j][r]);
      }
    }
  }
}

extern "C" void kernel_launch(void* const* d_in, const int* in_sizes, int n_in,
                              void* d_out, int out_size, void* d_ws, size_t ws_size,
                              hipStream_t stream) {
  const float* x  = (const float*)d_in[0];
  const float* wg = (const float*)d_in[1];
  const float* w1 = (const float*)d_in[2];
  const float* w3 = (const float*)d_in[3];
  const float* w2 = (const float*)d_in[4];
  float* out = (float*)d_out;
  char* ws = (char*)d_ws;

  size_t off = 0;
  int* hdr = (int*)(ws + off); off += 256;
  int* sel = (int*)(ws + off); off += (size_t)T_TOK * 2 * 4;
  float* prb = (float*)(ws + off); off += (size_t)T_TOK * 2 * 4;
  int* rows = (int*)(ws + off); off += (size_t)T_TOK * 2 * 4;
  float* prbs = (float*)(ws + off); off += (size_t)T_TOK * 2 * 4;
  unsigned short* xb  = (unsigned short*)(ws + off); off += (size_t)T_TOK * DDIM * 2;
  unsigned short* w1t = (unsigned short*)(ws + off); off += (size_t)EEXP * DDIM * FDIM * 2;
  unsigned short* w3t = (unsigned short*)(ws + off); off += (size_t)EEXP * DDIM * FDIM * 2;
  unsigned short* w2t = (unsigned short*)(ws + off); off += (size_t)EEXP * DDIM * FDIM * 2;
  unsigned short* h   = (unsigned short*)(ws + off); off += (size_t)T_TOK * 2 * FDIM * 2;

  hipMemsetAsync(hdr, 0, 256, stream);
  hipMemsetAsync(out, 0, (size_t)T_TOK * DDIM * sizeof(float), stream);

  castx_kernel<<<T_TOK * DDIM / 4 / 256, 256, 0, stream>>>(x, xb, T_TOK * DDIM / 4);
  transpose_cast3_kernel<<<dim3(32, 32, 24), 256, 0, stream>>>(w1, w3, w2, w1t, w3t, w2t);
  gate_kernel<<<T_TOK / 4, 256, 0, stream>>>(x, wg, sel, prb, hdr);
  scan_kernel<<<1, 64, 0, stream>>>(hdr);
  build_kernel<<<(T_TOK * 2 + 255) / 256, 256, 0, stream>>>(sel, prb, hdr, rows, prbs);
  gemm1_kernel<<<dim3(FDIM / 64, T_TOK / 128, EEXP), 256, 0, stream>>>(xb, w1t, w3t, rows, hdr, h);
  gemm2_kernel<<<dim3(DDIM / 128, T_TOK / 128, EEXP), 256, 0, stream>>>(h, w2t, rows, prbs, hdr, out);
}

// Round 3
// 841.260 us; speedup vs baseline: 1.0370x; 1.0370x over previous
//
#include <hip/hip_runtime.h>
#include <stdint.h>

#define T_TOK 8192
#define DDIM 1024
#define EEXP 8
#define FDIM 2048

typedef float f32x4 __attribute__((ext_vector_type(4)));
typedef __bf16 bf16x8 __attribute__((ext_vector_type(8)));
typedef unsigned short us8 __attribute__((ext_vector_type(8)));

#define VMCNT(N) asm volatile("s_waitcnt vmcnt(" #N ")" ::: "memory")
#define BAR() __builtin_amdgcn_s_barrier()

__device__ __forceinline__ unsigned short f2bf(float f) {
  union { float f; unsigned int u; } v; v.f = f;
  unsigned int r = (v.u + 0x7fffu + ((v.u >> 16) & 1u)) >> 16;
  return (unsigned short)r;
}

__device__ __forceinline__ void async_cp16(const void* g, void* l) {
  __builtin_amdgcn_global_load_lds(
      (const __attribute__((address_space(1))) unsigned int*)g,
      (__attribute__((address_space(3))) unsigned int*)l, 16, 0, 0);
}

// ---------------- cast x fp32 -> bf16 ----------------
__global__ __launch_bounds__(256) void castx_kernel(const float* __restrict__ in,
                                                    unsigned short* __restrict__ out,
                                                    int n4) {
  int i = blockIdx.x * 256 + threadIdx.x;
  if (i >= n4) return;
  float4 v = ((const float4*)in)[i];
  ushort4 o;
  o.x = f2bf(v.x); o.y = f2bf(v.y); o.z = f2bf(v.z); o.w = f2bf(v.w);
  ((ushort4*)out)[i] = o;
}

// ---------------- merged vectorized transpose-cast of w1/w3/w2 ----------------
__global__ __launch_bounds__(256) void transpose_cast3_kernel(
    const float* __restrict__ w1, const float* __restrict__ w3, const float* __restrict__ w2,
    unsigned short* __restrict__ w1t, unsigned short* __restrict__ w3t,
    unsigned short* __restrict__ w2t) {
  __shared__ float tile[64][65];
  const int z = blockIdx.z;
  const float* in;
  unsigned short* out;
  int R, C;
  if (z < 16) {
    R = DDIM; C = FDIM;
    const float* s = (z < 8) ? w1 : w3;
    unsigned short* o = (z < 8) ? w1t : w3t;
    in = s + (size_t)(z & 7) * R * C;
    out = o + (size_t)(z & 7) * R * C;
  } else {
    R = FDIM; C = DDIM;
    in = w2 + (size_t)(z & 7) * R * C;
    out = w2t + (size_t)(z & 7) * R * C;
  }
  const int c0 = blockIdx.x * 64;
  const int r0 = blockIdx.y * 64;
  if (c0 >= C || r0 >= R) return;
  const int t = threadIdx.x;
  const int pr = t >> 4;
  const int pc = (t & 15) * 4;
#pragma unroll
  for (int i = 0; i < 4; i++) {
    float4 v = *(const float4*)&in[(size_t)(r0 + pr + i * 16) * C + c0 + pc];
    tile[pr + i * 16][pc + 0] = v.x;
    tile[pr + i * 16][pc + 1] = v.y;
    tile[pr + i * 16][pc + 2] = v.z;
    tile[pr + i * 16][pc + 3] = v.w;
  }
  __syncthreads();
  const int qr = (t & 7) * 8;
  const int qc = t >> 3;
#pragma unroll
  for (int i = 0; i < 2; i++) {
    int cc = qc + i * 32;
    us8 o;
#pragma unroll
    for (int j = 0; j < 8; j++) o[j] = f2bf(tile[qr + j][cc]);
    *(us8*)&out[(size_t)(c0 + cc) * R + r0 + qr] = o;
  }
}

// ---------------- gating: wave per token ----------------
// hdr layout (ints): [0..7]=cnt, [8..15]=fill, [16..24]=offs
__global__ __launch_bounds__(256) void gate_kernel(const float* __restrict__ x,
                                                   const float* __restrict__ wg,
                                                   int* __restrict__ sel,
                                                   float* __restrict__ prb,
                                                   int* __restrict__ hdr) {
  __shared__ float wgs[8 * 1024];
  int tid = threadIdx.x;
  for (int i = tid; i < 8192; i += 256) {
    int d = i >> 3, e = i & 7;
    wgs[e * 1024 + d] = wg[i];
  }
  __syncthreads();
  int lane = tid & 63;
  int t = blockIdx.x * 4 + (tid >> 6);
  const float* xr = x + (size_t)t * 1024;
  float acc[8] = {0.f, 0.f, 0.f, 0.f, 0.f, 0.f, 0.f, 0.f};
  for (int d = lane; d < 1024; d += 64) {
    float xv = xr[d];
#pragma unroll
    for (int e = 0; e < 8; e++) acc[e] += xv * wgs[e * 1024 + d];
  }
#pragma unroll
  for (int e = 0; e < 8; e++) {
    acc[e] += __shfl_xor(acc[e], 32);
    acc[e] += __shfl_xor(acc[e], 16);
    acc[e] += __shfl_xor(acc[e], 8);
    acc[e] += __shfl_xor(acc[e], 4);
    acc[e] += __shfl_xor(acc[e], 2);
    acc[e] += __shfl_xor(acc[e], 1);
  }
  if (lane == 0) {
    int i0 = 0; float v0 = acc[0];
#pragma unroll
    for (int e = 1; e < 8; e++) if (acc[e] > v0) { v0 = acc[e]; i0 = e; }
    int i1 = -1; float v1 = -1e30f;
#pragma unroll
    for (int e = 0; e < 8; e++) if (e != i0 && acc[e] > v1) { v1 = acc[e]; i1 = e; }
    float ex = __expf(v1 - v0);
    float inv = 1.0f / (1.0f + ex);
    sel[t * 2] = i0; sel[t * 2 + 1] = i1;
    prb[t * 2] = inv; prb[t * 2 + 1] = ex * inv;
    atomicAdd(&hdr[i0], 1);
    atomicAdd(&hdr[i1], 1);
  }
}

__global__ void scan_kernel(int* hdr) {
  if (threadIdx.x == 0 && blockIdx.x == 0) {
    int s = 0;
    for (int e = 0; e < 8; e++) { hdr[16 + e] = s; s += hdr[e]; }
    hdr[24] = s;
  }
}

__global__ __launch_bounds__(256) void build_kernel(const int* __restrict__ sel,
                                                    const float* __restrict__ prb,
                                                    int* __restrict__ hdr,
                                                    int* __restrict__ rows,
                                                    int* __restrict__ slot_of) {
  int i = blockIdx.x * 256 + threadIdx.x;
  if (i >= T_TOK * 2) return;
  int e = sel[i];
  int pos = hdr[16 + e] + atomicAdd(&hdr[8 + e], 1);
  rows[pos] = i >> 1;
  slot_of[i] = pos;
}

// ======================= 8-phase counted-vmcnt GEMMs ========================
// LDS layout: [row][64] bf16 rows (128B), 16B-slot swizzle
//   phys_slot = logical_slot ^ (row & 7)  -> uniform 8 lanes/slot on ds_read_b128
// Stage-chunk <-> phase-read alignment (the round-2 bug): phase mh=0 reads rows
//   {0-63, 128-191} (both wave-group halves), mh=1 reads {64-127, 192-255}.
//   So stageA0 = quarters q0,q2; stageA1 = q1,q3.

// ---------------- GEMM1: h = silu(x@w1)*(x@w3) ------------------------------
// 256M x 128N dual-tensor, BK=64, 8 waves (2M x 4N), per-wave 128x32x{w1,w3}.
// Phases per K-tile: (mh0,w1) (mh0,w3) (mh1,w1) (mh1,w3), 16 MFMA each.
// Stage order for t+1: A0@ph0 B0@ph1 B1@ph2 A1@ph3; steady vmcnt 6/6/6/-.
__global__ __launch_bounds__(512, 2) void gemm1_kernel(
    const unsigned short* __restrict__ xb,   // [T][D] bf16
    const unsigned short* __restrict__ w1t,  // [E][F][D] bf16
    const unsigned short* __restrict__ w3t,  // [E][F][D] bf16
    const int* __restrict__ rows,
    const int* __restrict__ hdr,
    unsigned short* __restrict__ h)          // [T*2][F] bf16 (slot space)
{
  const int e = blockIdx.z;
  const int count = hdr[e];
  const int m0 = blockIdx.y * 256;
  if (m0 >= count) return;
  const int n0 = blockIdx.x * 128;
  const int sbase = hdr[16 + e];

  __shared__ unsigned short As[2][16384];  // 256 x 64
  __shared__ unsigned short Bs[2][16384];  // [w1:128 | w3:128] x 64

  const int tid = threadIdx.x;
  const int srcoff = ((tid & 7) ^ ((tid >> 3) & 7)) * 8;
  const int rq = tid >> 3;  // 0..63
  const unsigned short* pA[4];
#pragma unroll
  for (int q = 0; q < 4; q++) {
    int m = m0 + q * 64 + rq; if (m > count - 1) m = count - 1;
    pA[q] = xb + (size_t)rows[sbase + m] * DDIM + srcoff;
  }
  const unsigned short* pB[4];
  pB[0] = w1t + ((size_t)e * FDIM + n0 + rq) * DDIM + srcoff;
  pB[1] = w1t + ((size_t)e * FDIM + n0 + 64 + rq) * DDIM + srcoff;
  pB[2] = w3t + ((size_t)e * FDIM + n0 + rq) * DDIM + srcoff;
  pB[3] = w3t + ((size_t)e * FDIM + n0 + 64 + rq) * DDIM + srcoff;
  const int l0 = tid * 8;

  const int wv = tid >> 6;
  const int wr = (wv >> 2) * 128;   // 0 / 128
  const int wn = (wv & 3) * 32;     // 0..96
  const int lane = tid & 63;
  const int lm = lane & 15;
  const int ls = lane >> 4;
  const int coff0 = ((ls) ^ (lm & 7)) * 8;
  const int coff1 = ((4 + ls) ^ (lm & 7)) * 8;

  f32x4 acc1[8][2], acc3[8][2];
#pragma unroll
  for (int i = 0; i < 8; i++)
#pragma unroll
    for (int j = 0; j < 2; j++) {
      acc1[i][j] = f32x4{0.f, 0.f, 0.f, 0.f};
      acc3[i][j] = f32x4{0.f, 0.f, 0.f, 0.f};
    }

  bf16x8 a[8], b1[4], b3[4];

  // stageA0: rows 0-63 (q0) + rows 128-191 (q2)  [phase mh=0 reads these]
  auto stageA0 = [&](int buf, int kt) {
    async_cp16(pA[0] + kt, &As[buf][l0]);
    async_cp16(pA[2] + kt, &As[buf][8192 + l0]);
  };
  // stageA1: rows 64-127 (q1) + rows 192-255 (q3)  [phase mh=1]
  auto stageA1 = [&](int buf, int kt) {
    async_cp16(pA[1] + kt, &As[buf][4096 + l0]);
    async_cp16(pA[3] + kt, &As[buf][12288 + l0]);
  };
  auto stageB0 = [&](int buf, int kt) {
    async_cp16(pB[0] + kt, &Bs[buf][l0]);
    async_cp16(pB[1] + kt, &Bs[buf][4096 + l0]);
  };
  auto stageB1 = [&](int buf, int kt) {
    async_cp16(pB[2] + kt, &Bs[buf][8192 + l0]);
    async_cp16(pB[3] + kt, &Bs[buf][12288 + l0]);
  };
  auto rdA = [&](int cur, int mh) {
#pragma unroll
    for (int i = 0; i < 4; i++) {
      const unsigned short* rp = &As[cur][(wr + mh * 64 + i * 16 + lm) * 64];
      a[i * 2 + 0] = *(const bf16x8*)(rp + coff0);
      a[i * 2 + 1] = *(const bf16x8*)(rp + coff1);
    }
  };
  auto rdB = [&](int cur, int half, bf16x8* bb) {
#pragma unroll
    for (int j = 0; j < 2; j++) {
      const unsigned short* rp = &Bs[cur][(half * 128 + wn + j * 16 + lm) * 64];
      bb[j * 2 + 0] = *(const bf16x8*)(rp + coff0);
      bb[j * 2 + 1] = *(const bf16x8*)(rp + coff1);
    }
  };
  auto mm = [&](f32x4 (*acc)[2], int mh, bf16x8* bb) {
    __builtin_amdgcn_s_setprio(1);
#pragma unroll
    for (int i = 0; i < 4; i++)
#pragma unroll
      for (int j = 0; j < 2; j++) {
        f32x4 c = acc[mh * 4 + i][j];
        c = __builtin_amdgcn_mfma_f32_16x16x32_bf16(a[i * 2 + 0], bb[j * 2 + 0], c, 0, 0, 0);
        c = __builtin_amdgcn_mfma_f32_16x16x32_bf16(a[i * 2 + 1], bb[j * 2 + 1], c, 0, 0, 0);
        acc[mh * 4 + i][j] = c;
      }
    __builtin_amdgcn_s_setprio(0);
  };

  // prologue: tile 0, consumption order A0,B0 | B1 | A1
  stageA0(0, 0); stageB0(0, 0); stageB1(0, 0); stageA1(0, 0);

  for (int t = 0; t < 15; ++t) {
    const int cur = t & 1, nxt = cur ^ 1;
    const int kt = (t + 1) * 64;
    stageA0(nxt, kt); VMCNT(6); BAR();          // A0(t),B0(t) landed
    rdA(cur, 0); rdB(cur, 0, b1); mm(acc1, 0, b1);
    stageB0(nxt, kt); VMCNT(6); BAR();          // B1(t) landed
    rdB(cur, 1, b3); mm(acc3, 0, b3);
    stageB1(nxt, kt); VMCNT(6); BAR();          // A1(t) landed
    rdA(cur, 1); mm(acc1, 1, b1);
    stageA1(nxt, kt); BAR();
    mm(acc3, 1, b3);
  }
  {  // tail t=15 (cur=1), no staging; queue [A0,B0,B1,A1]=8
    VMCNT(4); BAR(); rdA(1, 0); rdB(1, 0, b1); mm(acc1, 0, b1);
    VMCNT(2); BAR(); rdB(1, 1, b3); mm(acc3, 0, b3);
    VMCNT(0); BAR(); rdA(1, 1); mm(acc1, 1, b1);
    BAR(); mm(acc3, 1, b3);
  }

#pragma unroll
  for (int i = 0; i < 8; i++) {
#pragma unroll
    for (int r = 0; r < 4; r++) {
      int mg = m0 + wr + i * 16 + ls * 4 + r;
      if (mg < count) {
        unsigned short* hp = h + (size_t)(sbase + mg) * FDIM + n0 + wn + lm;
#pragma unroll
        for (int j = 0; j < 2; j++) {
          float v1 = acc1[i][j][r];
          float v3 = acc3[i][j][r];
          float hv = (v1 / (1.0f + __expf(-v1))) * v3;
          hp[j * 16] = f2bf(hv);
        }
      }
    }
  }
}

// ---------------- GEMM2: y[slot] = h[slot] @ w2 ------------------------------
// 256M x 256N, BK=64, 8 waves (2M x 4N), per-wave 128x64 (m201 geometry).
// Phases per K-tile: (mh0,kk0) (mh0,kk1) (mh1,kk0) (mh1,kk1), 16 MFMA each.
// Phase 0 reads ALL of B (per-wave panels) + A quarters q0,q2.
// Stage order for t+1: B0@ph0 B1@ph1 A0@ph2 A1@ph3; steady vmcnt 4/-/6/-.
__global__ __launch_bounds__(512, 2) void gemm2_kernel(
    const unsigned short* __restrict__ h,    // [T*2][F] bf16
    const unsigned short* __restrict__ w2t,  // [E][D][F] bf16
    const int* __restrict__ hdr,
    float* __restrict__ y)                   // [T*2][D] fp32 (slot space)
{
  const int e = blockIdx.z;
  const int count = hdr[e];
  const int m0 = blockIdx.y * 256;
  if (m0 >= count) return;
  const int n0 = blockIdx.x * 256;
  const int sbase = hdr[16 + e];

  __shared__ unsigned short As[2][16384];  // 256 x 64
  __shared__ unsigned short Bs[2][16384];  // 256 x 64

  const int tid = threadIdx.x;
  const int srcoff = ((tid & 7) ^ ((tid >> 3) & 7)) * 8;
  const int rq = tid >> 3;
  const unsigned short* pA[4];
#pragma unroll
  for (int q = 0; q < 4; q++) {
    int m = m0 + q * 64 + rq; if (m > count - 1) m = count - 1;
    pA[q] = h + (size_t)(sbase + m) * FDIM + srcoff;
  }
  const unsigned short* pB[4];
#pragma unroll
  for (int q = 0; q < 4; q++)
    pB[q] = w2t + ((size_t)e * DDIM + n0 + q * 64 + rq) * FDIM + srcoff;
  const int l0 = tid * 8;

  const int wv = tid >> 6;
  const int wr = (wv >> 2) * 128;
  const int wn = (wv & 3) * 64;
  const int lane = tid & 63;
  const int lm = lane & 15;
  const int ls = lane >> 4;
  const int coff0 = ((ls) ^ (lm & 7)) * 8;
  const int coff1 = ((4 + ls) ^ (lm & 7)) * 8;

  f32x4 acc[8][4];
#pragma unroll
  for (int i = 0; i < 8; i++)
#pragma unroll
    for (int j = 0; j < 4; j++) acc[i][j] = f32x4{0.f, 0.f, 0.f, 0.f};

  bf16x8 a[8], b[8];  // a[kk*4+i], b[kk*4+j]

  // stageA0: rows 0-63 (q0) + 128-191 (q2); stageA1: 64-127 (q1) + 192-255 (q3)
  auto stageA0 = [&](int buf, int kt) {
    async_cp16(pA[0] + kt, &As[buf][l0]);
    async_cp16(pA[2] + kt, &As[buf][8192 + l0]);
  };
  auto stageA1 = [&](int buf, int kt) {
    async_cp16(pA[1] + kt, &As[buf][4096 + l0]);
    async_cp16(pA[3] + kt, &As[buf][12288 + l0]);
  };
  auto stageB0 = [&](int buf, int kt) {
    async_cp16(pB[0] + kt, &Bs[buf][l0]);
    async_cp16(pB[1] + kt, &Bs[buf][4096 + l0]);
  };
  auto stageB1 = [&](int buf, int kt) {
    async_cp16(pB[2] + kt, &Bs[buf][8192 + l0]);
    async_cp16(pB[3] + kt, &Bs[buf][12288 + l0]);
  };
  auto rdA2 = [&](int cur, int mh, int kk) {
#pragma unroll
    for (int i = 0; i < 4; i++) {
      const unsigned short* rp = &As[cur][(wr + mh * 64 + i * 16 + lm) * 64];
      a[kk * 4 + i] = *(const bf16x8*)(rp + (kk ? coff1 : coff0));
    }
  };
  auto rdB2 = [&](int cur, int kk) {
#pragma unroll
    for (int j = 0; j < 4; j++) {
      const unsigned short* rp = &Bs[cur][(wn + j * 16 + lm) * 64];
      b[kk * 4 + j] = *(const bf16x8*)(rp + (kk ? coff1 : coff0));
    }
  };
  auto mm2 = [&](int mh, int kk) {
    __builtin_amdgcn_s_setprio(1);
#pragma unroll
    for (int i = 0; i < 4; i++)
#pragma unroll
      for (int j = 0; j < 4; j++)
        acc[mh * 4 + i][j] =
            __builtin_amdgcn_mfma_f32_16x16x32_bf16(a[kk * 4 + i], b[kk * 4 + j],
                                                    acc[mh * 4 + i][j], 0, 0, 0);
    __builtin_amdgcn_s_setprio(0);
  };

  // prologue: tile 0, consumption order B0,B1,A0 | A1
  stageB0(0, 0); stageB1(0, 0); stageA0(0, 0); stageA1(0, 0);

  for (int t = 0; t < 31; ++t) {
    const int cur = t & 1, nxt = cur ^ 1;
    const int kt = (t + 1) * 64;
    stageB0(nxt, kt); VMCNT(4); BAR();          // B0,B1,A0(t) landed
    rdA2(cur, 0, 0); rdB2(cur, 0); mm2(0, 0);
    stageB1(nxt, kt); BAR();
    rdA2(cur, 0, 1); rdB2(cur, 1); mm2(0, 1);
    stageA0(nxt, kt); VMCNT(6); BAR();          // A1(t) landed
    rdA2(cur, 1, 0); mm2(1, 0);
    stageA1(nxt, kt); BAR();
    rdA2(cur, 1, 1); mm2(1, 1);
  }
  {  // tail t=31 (cur=1), no staging; queue [B0,B1,A0,A1]=8
    VMCNT(2); BAR(); rdA2(1, 0, 0); rdB2(1, 0); mm2(0, 0);
    BAR(); rdA2(1, 0, 1); rdB2(1, 1); mm2(0, 1);
    VMCNT(0); BAR(); rdA2(1, 1, 0); mm2(1, 0);
    BAR(); rdA2(1, 1, 1); mm2(1, 1);
  }

#pragma unroll
  for (int i = 0; i < 8; i++) {
#pragma unroll
    for (int r = 0; r < 4; r++) {
      int mg = m0 + wr + i * 16 + ls * 4 + r;
      if (mg < count) {
        float* yp = y + (size_t)(sbase + mg) * DDIM + n0 + wn + lm;
#pragma unroll
        for (int j = 0; j < 4; j++) yp[j * 16] = acc[i][j][r];
      }
    }
  }
}

// ---------------- combine: out[t] = p0*y[s0] + p1*y[s1] ----------------
__global__ __launch_bounds__(256) void combine_kernel(const float* __restrict__ y,
                                                      const int* __restrict__ slot_of,
                                                      const float* __restrict__ prb,
                                                      float* __restrict__ out) {
  int t = blockIdx.x;
  int s0 = slot_of[t * 2], s1 = slot_of[t * 2 + 1];
  float p0 = prb[t * 2], p1 = prb[t * 2 + 1];
  float4 a = ((const float4*)(y + (size_t)s0 * DDIM))[threadIdx.x];
  float4 b = ((const float4*)(y + (size_t)s1 * DDIM))[threadIdx.x];
  float4 o;
  o.x = p0 * a.x + p1 * b.x;
  o.y = p0 * a.y + p1 * b.y;
  o.z = p0 * a.z + p1 * b.z;
  o.w = p0 * a.w + p1 * b.w;
  ((float4*)(out + (size_t)t * DDIM))[threadIdx.x] = o;
}

extern "C" void kernel_launch(void* const* d_in, const int* in_sizes, int n_in,
                              void* d_out, int out_size, void* d_ws, size_t ws_size,
                              hipStream_t stream) {
  const float* x  = (const float*)d_in[0];
  const float* wg = (const float*)d_in[1];
  const float* w1 = (const float*)d_in[2];
  const float* w3 = (const float*)d_in[3];
  const float* w2 = (const float*)d_in[4];
  float* out = (float*)d_out;
  char* ws = (char*)d_ws;

  size_t off = 0;
  int* hdr = (int*)(ws + off); off += 256;
  int* sel = (int*)(ws + off); off += (size_t)T_TOK * 2 * 4;
  float* prb = (float*)(ws + off); off += (size_t)T_TOK * 2 * 4;
  int* rows = (int*)(ws + off); off += (size_t)T_TOK * 2 * 4;
  int* slot_of = (int*)(ws + off); off += (size_t)T_TOK * 2 * 4;
  unsigned short* xb  = (unsigned short*)(ws + off); off += (size_t)T_TOK * DDIM * 2;
  unsigned short* w1t = (unsigned short*)(ws + off); off += (size_t)EEXP * DDIM * FDIM * 2;
  unsigned short* w3t = (unsigned short*)(ws + off); off += (size_t)EEXP * DDIM * FDIM * 2;
  unsigned short* w2t = (unsigned short*)(ws + off); off += (size_t)EEXP * DDIM * FDIM * 2;
  unsigned short* h   = (unsigned short*)(ws + off); off += (size_t)T_TOK * 2 * FDIM * 2;
  // y overlays w1t+w3t (64 MB, dead after gemm1): [T*2][D] fp32
  float* y = (float*)w1t;

  hipMemsetAsync(hdr, 0, 256, stream);

  castx_kernel<<<T_TOK * DDIM / 4 / 256, 256, 0, stream>>>(x, xb, T_TOK * DDIM / 4);
  transpose_cast3_kernel<<<dim3(32, 32, 24), 256, 0, stream>>>(w1, w3, w2, w1t, w3t, w2t);
  gate_kernel<<<T_TOK / 4, 256, 0, stream>>>(x, wg, sel, prb, hdr);
  scan_kernel<<<1, 64, 0, stream>>>(hdr);
  build_kernel<<<(T_TOK * 2 + 255) / 256, 256, 0, stream>>>(sel, prb, hdr, rows, slot_of);
  gemm1_kernel<<<dim3(FDIM / 128, T_TOK / 128 / 2, EEXP), 512, 0, stream>>>(xb, w1t, w3t, rows, hdr, h);
  gemm2_kernel<<<dim3(DDIM / 256, T_TOK / 128 / 2, EEXP), 512, 0, stream>>>(h, w2t, hdr, y);
  combine_kernel<<<T_TOK, 256, 0, stream>>>(y, slot_of, prb, out);
}

// Round 4
// 568.430 us; speedup vs baseline: 1.5347x; 1.4800x over previous
//
#include <hip/hip_runtime.h>
#include <stdint.h>

#define T_TOK 8192
#define DDIM 1024
#define EEXP 8
#define FDIM 2048
#define GBLK 512   // gate blocks; 16 tokens each

typedef float f32x4 __attribute__((ext_vector_type(4)));
typedef __bf16 bf16x8 __attribute__((ext_vector_type(8)));
typedef unsigned short us8 __attribute__((ext_vector_type(8)));

#define VMCNT(N) asm volatile("s_waitcnt vmcnt(" #N ")" ::: "memory")
#define BAR() __builtin_amdgcn_s_barrier()

__device__ __forceinline__ unsigned short f2bf(float f) {
  union { float f; unsigned int u; } v; v.f = f;
  unsigned int r = (v.u + 0x7fffu + ((v.u >> 16) & 1u)) >> 16;
  return (unsigned short)r;
}

__device__ __forceinline__ void async_cp16(const void* g, void* l) {
  __builtin_amdgcn_global_load_lds(
      (const __attribute__((address_space(1))) unsigned int*)g,
      (__attribute__((address_space(3))) unsigned int*)l, 16, 0, 0);
}

// ---------------- merged vectorized transpose-cast of w1/w3/w2 ----------------
__global__ __launch_bounds__(256) void transpose_cast3_kernel(
    const float* __restrict__ w1, const float* __restrict__ w3, const float* __restrict__ w2,
    unsigned short* __restrict__ w1t, unsigned short* __restrict__ w3t,
    unsigned short* __restrict__ w2t) {
  __shared__ float tile[64][65];
  const int z = blockIdx.z;
  const float* in;
  unsigned short* out;
  int R, C;
  if (z < 16) {
    R = DDIM; C = FDIM;
    const float* s = (z < 8) ? w1 : w3;
    unsigned short* o = (z < 8) ? w1t : w3t;
    in = s + (size_t)(z & 7) * R * C;
    out = o + (size_t)(z & 7) * R * C;
  } else {
    R = FDIM; C = DDIM;
    in = w2 + (size_t)(z & 7) * R * C;
    out = w2t + (size_t)(z & 7) * R * C;
  }
  const int c0 = blockIdx.x * 64;
  const int r0 = blockIdx.y * 64;
  if (c0 >= C || r0 >= R) return;
  const int t = threadIdx.x;
  const int pr = t >> 4;
  const int pc = (t & 15) * 4;
#pragma unroll
  for (int i = 0; i < 4; i++) {
    float4 v = *(const float4*)&in[(size_t)(r0 + pr + i * 16) * C + c0 + pc];
    tile[pr + i * 16][pc + 0] = v.x;
    tile[pr + i * 16][pc + 1] = v.y;
    tile[pr + i * 16][pc + 2] = v.z;
    tile[pr + i * 16][pc + 3] = v.w;
  }
  __syncthreads();
  const int qr = (t & 7) * 8;
  const int qc = t >> 3;
#pragma unroll
  for (int i = 0; i < 2; i++) {
    int cc = qc + i * 32;
    us8 o;
#pragma unroll
    for (int j = 0; j < 8; j++) o[j] = f2bf(tile[qr + j][cc]);
    *(us8*)&out[(size_t)(c0 + cc) * R + r0 + qr] = o;
  }
}

// ---------------- gating + fused x cast: NO global atomics ----------------
// 512 blocks x 16 tokens. Wave per token (4 waves, 4 rounds). float4 x loads,
// fused bf16 cast of x into xb, LDS histogram -> cnt_blk[block][8].
__global__ __launch_bounds__(256) void gate_kernel(const float* __restrict__ x,
                                                   const float* __restrict__ wg,
                                                   unsigned short* __restrict__ xb,
                                                   int* __restrict__ sel,
                                                   float* __restrict__ prb,
                                                   int* __restrict__ cnt_blk) {
  __shared__ float wgs[8 * 1024];  // [e][d]
  __shared__ int cnt[8];
  const int tid = threadIdx.x;
  if (tid < 8) cnt[tid] = 0;
  for (int i = tid; i < 8192; i += 256) {
    int d = i >> 3, e = i & 7;
    wgs[e * 1024 + d] = wg[i];
  }
  __syncthreads();
  const int lane = tid & 63;
  const int wv = tid >> 6;
#pragma unroll 1
  for (int tt = 0; tt < 4; tt++) {
    const int t = blockIdx.x * 16 + tt * 4 + wv;
    const float4* xp = (const float4*)(x + (size_t)t * 1024);
    float4 xv[4];
#pragma unroll
    for (int it = 0; it < 4; it++) xv[it] = xp[lane + it * 64];
    float acc[8] = {0.f, 0.f, 0.f, 0.f, 0.f, 0.f, 0.f, 0.f};
    ushort4* xbp = (ushort4*)(xb + (size_t)t * 1024);
#pragma unroll
    for (int it = 0; it < 4; it++) {
      const int d = (lane + it * 64) * 4;
      float4 v = xv[it];
      ushort4 o;
      o.x = f2bf(v.x); o.y = f2bf(v.y); o.z = f2bf(v.z); o.w = f2bf(v.w);
      xbp[lane + it * 64] = o;
#pragma unroll
      for (int e = 0; e < 8; e++)
        acc[e] += v.x * wgs[e * 1024 + d] + v.y * wgs[e * 1024 + d + 1] +
                  v.z * wgs[e * 1024 + d + 2] + v.w * wgs[e * 1024 + d + 3];
    }
#pragma unroll
    for (int e = 0; e < 8; e++) {
      acc[e] += __shfl_xor(acc[e], 32);
      acc[e] += __shfl_xor(acc[e], 16);
      acc[e] += __shfl_xor(acc[e], 8);
      acc[e] += __shfl_xor(acc[e], 4);
      acc[e] += __shfl_xor(acc[e], 2);
      acc[e] += __shfl_xor(acc[e], 1);
    }
    if (lane == 0) {
      int i0 = 0; float v0 = acc[0];
#pragma unroll
      for (int e = 1; e < 8; e++) if (acc[e] > v0) { v0 = acc[e]; i0 = e; }
      int i1 = -1; float v1 = -1e30f;
#pragma unroll
      for (int e = 0; e < 8; e++) if (e != i0 && acc[e] > v1) { v1 = acc[e]; i1 = e; }
      float ex = __expf(v1 - v0);
      float inv = 1.0f / (1.0f + ex);
      sel[t * 2] = i0; sel[t * 2 + 1] = i1;
      prb[t * 2] = inv; prb[t * 2 + 1] = ex * inv;
      atomicAdd(&cnt[i0], 1);   // LDS atomics only
      atomicAdd(&cnt[i1], 1);
    }
  }
  __syncthreads();
  if (tid < 8) cnt_blk[blockIdx.x * 8 + tid] = cnt[tid];
}

// ---------------- scan: totals, expert offsets, per-gate-block offsets -------
// hdr: [0..7]=cnt, [16..23]=offs, [24]=total. blk_off[GBLK][8].
__global__ __launch_bounds__(64) void scan_kernel(const int* __restrict__ cnt_blk,
                                                  int* __restrict__ hdr,
                                                  int* __restrict__ blk_off) {
  __shared__ int part[64];
  const int i = threadIdx.x;       // 0..63
  const int e = i & 7, chunk = i >> 3;  // 8 chunks of GBLK/8 blocks
  const int CPB = GBLK / 8;
  int s = 0;
  for (int b = 0; b < CPB; b++) s += cnt_blk[(chunk * CPB + b) * 8 + e];
  part[i] = s;
  __syncthreads();
  if (i < 8) {
    int tot = 0;
#pragma unroll
    for (int c = 0; c < 8; c++) tot += part[c * 8 + i];
    hdr[i] = tot;
  }
  __syncthreads();
  if (i == 0) {
    int s2 = 0;
    for (int e2 = 0; e2 < 8; e2++) { hdr[16 + e2] = s2; s2 += hdr[e2]; }
    hdr[24] = s2;
  }
  __syncthreads();
  int running = hdr[16 + e];
  for (int c = 0; c < chunk; c++) running += part[c * 8 + e];
  for (int b = 0; b < CPB; b++) {
    int idx = (chunk * CPB + b) * 8 + e;
    blk_off[idx] = running;
    running += cnt_blk[idx];
  }
}

// ---------------- build: ballot-ranked, deterministic, no atomics ------------
// Each gate-block owns 32 items (16 tokens x 2). One wave covers 2 gate-blocks.
__global__ __launch_bounds__(64) void build_kernel(const int* __restrict__ sel,
                                                   const int* __restrict__ blk_off,
                                                   int* __restrict__ rows,
                                                   int* __restrict__ slot_of) {
  const int lane = threadIdx.x;
  const int i = blockIdx.x * 64 + lane;   // item id
  const int gb = i >> 5;                  // gate block
  const int e = sel[i];
  unsigned long long m = 0;
#pragma unroll
  for (int ee = 0; ee < 8; ee++) {
    unsigned long long be = __ballot(e == ee);
    if (ee == e) m = be;
  }
  const unsigned long long half =
      (lane < 32) ? 0x00000000FFFFFFFFull : 0xFFFFFFFF00000000ull;
  const unsigned long long below = (1ull << lane) - 1ull;
  const int rank = __popcll(m & half & below);
  const int pos = blk_off[gb * 8 + e] + rank;
  rows[pos] = i >> 1;
  slot_of[i] = pos;
}

// ======================= 8-phase counted-vmcnt GEMMs ========================
// LDS layout: [row][64] bf16 rows (128B), 16B-slot swizzle
//   phys_slot = logical_slot ^ (row & 7); stageA0 = quarters q0,q2 (phase mh=0
//   rows {0-63,128-191}); stageA1 = q1,q3.

// ---------------- GEMM1: h = silu(x@w1)*(x@w3) ------------------------------
__global__ __launch_bounds__(512, 2) void gemm1_kernel(
    const unsigned short* __restrict__ xb,   // [T][D] bf16
    const unsigned short* __restrict__ w1t,  // [E][F][D] bf16
    const unsigned short* __restrict__ w3t,  // [E][F][D] bf16
    const int* __restrict__ rows,
    const int* __restrict__ hdr,
    unsigned short* __restrict__ h)          // [T*2][F] bf16 (slot space)
{
  const int e = blockIdx.z;
  const int count = hdr[e];
  const int m0 = blockIdx.y * 256;
  if (m0 >= count) return;
  const int n0 = blockIdx.x * 128;
  const int sbase = hdr[16 + e];

  __shared__ unsigned short As[2][16384];  // 256 x 64
  __shared__ unsigned short Bs[2][16384];  // [w1:128 | w3:128] x 64

  const int tid = threadIdx.x;
  const int srcoff = ((tid & 7) ^ ((tid >> 3) & 7)) * 8;
  const int rq = tid >> 3;  // 0..63
  const unsigned short* pA[4];
#pragma unroll
  for (int q = 0; q < 4; q++) {
    int m = m0 + q * 64 + rq; if (m > count - 1) m = count - 1;
    pA[q] = xb + (size_t)rows[sbase + m] * DDIM + srcoff;
  }
  const unsigned short* pB[4];
  pB[0] = w1t + ((size_t)e * FDIM + n0 + rq) * DDIM + srcoff;
  pB[1] = w1t + ((size_t)e * FDIM + n0 + 64 + rq) * DDIM + srcoff;
  pB[2] = w3t + ((size_t)e * FDIM + n0 + rq) * DDIM + srcoff;
  pB[3] = w3t + ((size_t)e * FDIM + n0 + 64 + rq) * DDIM + srcoff;
  const int l0 = tid * 8;

  const int wv = tid >> 6;
  const int wr = (wv >> 2) * 128;   // 0 / 128
  const int wn = (wv & 3) * 32;     // 0..96
  const int lane = tid & 63;
  const int lm = lane & 15;
  const int ls = lane >> 4;
  const int coff0 = ((ls) ^ (lm & 7)) * 8;
  const int coff1 = ((4 + ls) ^ (lm & 7)) * 8;

  f32x4 acc1[8][2], acc3[8][2];
#pragma unroll
  for (int i = 0; i < 8; i++)
#pragma unroll
    for (int j = 0; j < 2; j++) {
      acc1[i][j] = f32x4{0.f, 0.f, 0.f, 0.f};
      acc3[i][j] = f32x4{0.f, 0.f, 0.f, 0.f};
    }

  bf16x8 a[8], b1[4], b3[4];

  auto stageA0 = [&](int buf, int kt) {
    async_cp16(pA[0] + kt, &As[buf][l0]);
    async_cp16(pA[2] + kt, &As[buf][8192 + l0]);
  };
  auto stageA1 = [&](int buf, int kt) {
    async_cp16(pA[1] + kt, &As[buf][4096 + l0]);
    async_cp16(pA[3] + kt, &As[buf][12288 + l0]);
  };
  auto stageB0 = [&](int buf, int kt) {
    async_cp16(pB[0] + kt, &Bs[buf][l0]);
    async_cp16(pB[1] + kt, &Bs[buf][4096 + l0]);
  };
  auto stageB1 = [&](int buf, int kt) {
    async_cp16(pB[2] + kt, &Bs[buf][8192 + l0]);
    async_cp16(pB[3] + kt, &Bs[buf][12288 + l0]);
  };
  auto rdA = [&](int cur, int mh) {
#pragma unroll
    for (int i = 0; i < 4; i++) {
      const unsigned short* rp = &As[cur][(wr + mh * 64 + i * 16 + lm) * 64];
      a[i * 2 + 0] = *(const bf16x8*)(rp + coff0);
      a[i * 2 + 1] = *(const bf16x8*)(rp + coff1);
    }
  };
  auto rdB = [&](int cur, int half, bf16x8* bb) {
#pragma unroll
    for (int j = 0; j < 2; j++) {
      const unsigned short* rp = &Bs[cur][(half * 128 + wn + j * 16 + lm) * 64];
      bb[j * 2 + 0] = *(const bf16x8*)(rp + coff0);
      bb[j * 2 + 1] = *(const bf16x8*)(rp + coff1);
    }
  };
  auto mm = [&](f32x4 (*acc)[2], int mh, bf16x8* bb) {
    __builtin_amdgcn_s_setprio(1);
#pragma unroll
    for (int i = 0; i < 4; i++)
#pragma unroll
      for (int j = 0; j < 2; j++) {
        f32x4 c = acc[mh * 4 + i][j];
        c = __builtin_amdgcn_mfma_f32_16x16x32_bf16(a[i * 2 + 0], bb[j * 2 + 0], c, 0, 0, 0);
        c = __builtin_amdgcn_mfma_f32_16x16x32_bf16(a[i * 2 + 1], bb[j * 2 + 1], c, 0, 0, 0);
        acc[mh * 4 + i][j] = c;
      }
    __builtin_amdgcn_s_setprio(0);
  };

  // prologue: tile 0, consumption order A0,B0 | B1 | A1
  stageA0(0, 0); stageB0(0, 0); stageB1(0, 0); stageA1(0, 0);

  for (int t = 0; t < 15; ++t) {
    const int cur = t & 1, nxt = cur ^ 1;
    const int kt = (t + 1) * 64;
    stageA0(nxt, kt); VMCNT(6); BAR();          // A0(t),B0(t) landed
    rdA(cur, 0); rdB(cur, 0, b1); mm(acc1, 0, b1);
    stageB0(nxt, kt); VMCNT(6); BAR();          // B1(t) landed
    rdB(cur, 1, b3); mm(acc3, 0, b3);
    stageB1(nxt, kt); VMCNT(6); BAR();          // A1(t) landed
    rdA(cur, 1); mm(acc1, 1, b1);
    stageA1(nxt, kt); BAR();
    mm(acc3, 1, b3);
  }
  {  // tail t=15 (cur=1), no staging; queue [A0,B0,B1,A1]=8
    VMCNT(4); BAR(); rdA(1, 0); rdB(1, 0, b1); mm(acc1, 0, b1);
    VMCNT(2); BAR(); rdB(1, 1, b3); mm(acc3, 0, b3);
    VMCNT(0); BAR(); rdA(1, 1); mm(acc1, 1, b1);
    BAR(); mm(acc3, 1, b3);
  }

#pragma unroll
  for (int i = 0; i < 8; i++) {
#pragma unroll
    for (int r = 0; r < 4; r++) {
      int mg = m0 + wr + i * 16 + ls * 4 + r;
      if (mg < count) {
        unsigned short* hp = h + (size_t)(sbase + mg) * FDIM + n0 + wn + lm;
#pragma unroll
        for (int j = 0; j < 2; j++) {
          float v1 = acc1[i][j][r];
          float v3 = acc3[i][j][r];
          float hv = (v1 / (1.0f + __expf(-v1))) * v3;
          hp[j * 16] = f2bf(hv);
        }
      }
    }
  }
}

// ---------------- GEMM2: y[slot] = h[slot] @ w2 ------------------------------
__global__ __launch_bounds__(512, 2) void gemm2_kernel(
    const unsigned short* __restrict__ h,    // [T*2][F] bf16
    const unsigned short* __restrict__ w2t,  // [E][D][F] bf16
    const int* __restrict__ hdr,
    float* __restrict__ y)                   // [T*2][D] fp32 (slot space)
{
  const int e = blockIdx.z;
  const int count = hdr[e];
  const int m0 = blockIdx.y * 256;
  if (m0 >= count) return;
  const int n0 = blockIdx.x * 256;
  const int sbase = hdr[16 + e];

  __shared__ unsigned short As[2][16384];  // 256 x 64
  __shared__ unsigned short Bs[2][16384];  // 256 x 64

  const int tid = threadIdx.x;
  const int srcoff = ((tid & 7) ^ ((tid >> 3) & 7)) * 8;
  const int rq = tid >> 3;
  const unsigned short* pA[4];
#pragma unroll
  for (int q = 0; q < 4; q++) {
    int m = m0 + q * 64 + rq; if (m > count - 1) m = count - 1;
    pA[q] = h + (size_t)(sbase + m) * FDIM + srcoff;
  }
  const unsigned short* pB[4];
#pragma unroll
  for (int q = 0; q < 4; q++)
    pB[q] = w2t + ((size_t)e * DDIM + n0 + q * 64 + rq) * FDIM + srcoff;
  const int l0 = tid * 8;

  const int wv = tid >> 6;
  const int wr = (wv >> 2) * 128;
  const int wn = (wv & 3) * 64;
  const int lane = tid & 63;
  const int lm = lane & 15;
  const int ls = lane >> 4;
  const int coff0 = ((ls) ^ (lm & 7)) * 8;
  const int coff1 = ((4 + ls) ^ (lm & 7)) * 8;

  f32x4 acc[8][4];
#pragma unroll
  for (int i = 0; i < 8; i++)
#pragma unroll
    for (int j = 0; j < 4; j++) acc[i][j] = f32x4{0.f, 0.f, 0.f, 0.f};

  bf16x8 a[8], b[8];

  auto stageA0 = [&](int buf, int kt) {
    async_cp16(pA[0] + kt, &As[buf][l0]);
    async_cp16(pA[2] + kt, &As[buf][8192 + l0]);
  };
  auto stageA1 = [&](int buf, int kt) {
    async_cp16(pA[1] + kt, &As[buf][4096 + l0]);
    async_cp16(pA[3] + kt, &As[buf][12288 + l0]);
  };
  auto stageB0 = [&](int buf, int kt) {
    async_cp16(pB[0] + kt, &Bs[buf][l0]);
    async_cp16(pB[1] + kt, &Bs[buf][4096 + l0]);
  };
  auto stageB1 = [&](int buf, int kt) {
    async_cp16(pB[2] + kt, &Bs[buf][8192 + l0]);
    async_cp16(pB[3] + kt, &Bs[buf][12288 + l0]);
  };
  auto rdA2 = [&](int cur, int mh, int kk) {
#pragma unroll
    for (int i = 0; i < 4; i++) {
      const unsigned short* rp = &As[cur][(wr + mh * 64 + i * 16 + lm) * 64];
      a[kk * 4 + i] = *(const bf16x8*)(rp + (kk ? coff1 : coff0));
    }
  };
  auto rdB2 = [&](int cur, int kk) {
#pragma unroll
    for (int j = 0; j < 4; j++) {
      const unsigned short* rp = &Bs[cur][(wn + j * 16 + lm) * 64];
      b[kk * 4 + j] = *(const bf16x8*)(rp + (kk ? coff1 : coff0));
    }
  };
  auto mm2 = [&](int mh, int kk) {
    __builtin_amdgcn_s_setprio(1);
#pragma unroll
    for (int i = 0; i < 4; i++)
#pragma unroll
      for (int j = 0; j < 4; j++)
        acc[mh * 4 + i][j] =
            __builtin_amdgcn_mfma_f32_16x16x32_bf16(a[kk * 4 + i], b[kk * 4 + j],
                                                    acc[mh * 4 + i][j], 0, 0, 0);
    __builtin_amdgcn_s_setprio(0);
  };

  // prologue: tile 0, consumption order B0,B1,A0 | A1
  stageB0(0, 0); stageB1(0, 0); stageA0(0, 0); stageA1(0, 0);

  for (int t = 0; t < 31; ++t) {
    const int cur = t & 1, nxt = cur ^ 1;
    const int kt = (t + 1) * 64;
    stageB0(nxt, kt); VMCNT(4); BAR();          // B0,B1,A0(t) landed
    rdA2(cur, 0, 0); rdB2(cur, 0); mm2(0, 0);
    stageB1(nxt, kt); BAR();
    rdA2(cur, 0, 1); rdB2(cur, 1); mm2(0, 1);
    stageA0(nxt, kt); VMCNT(6); BAR();          // A1(t) landed
    rdA2(cur, 1, 0); mm2(1, 0);
    stageA1(nxt, kt); BAR();
    rdA2(cur, 1, 1); mm2(1, 1);
  }
  {  // tail t=31 (cur=1), no staging; queue [B0,B1,A0,A1]=8
    VMCNT(2); BAR(); rdA2(1, 0, 0); rdB2(1, 0); mm2(0, 0);
    BAR(); rdA2(1, 0, 1); rdB2(1, 1); mm2(0, 1);
    VMCNT(0); BAR(); rdA2(1, 1, 0); mm2(1, 0);
    BAR(); rdA2(1, 1, 1); mm2(1, 1);
  }

#pragma unroll
  for (int i = 0; i < 8; i++) {
#pragma unroll
    for (int r = 0; r < 4; r++) {
      int mg = m0 + wr + i * 16 + ls * 4 + r;
      if (mg < count) {
        float* yp = y + (size_t)(sbase + mg) * DDIM + n0 + wn + lm;
#pragma unroll
        for (int j = 0; j < 4; j++) yp[j * 16] = acc[i][j][r];
      }
    }
  }
}

// ---------------- combine: out[t] = p0*y[s0] + p1*y[s1] ----------------
__global__ __launch_bounds__(256) void combine_kernel(const float* __restrict__ y,
                                                      const int* __restrict__ slot_of,
                                                      const float* __restrict__ prb,
                                                      float* __restrict__ out) {
  int t = blockIdx.x;
  int s0 = slot_of[t * 2], s1 = slot_of[t * 2 + 1];
  float p0 = prb[t * 2], p1 = prb[t * 2 + 1];
  float4 a = ((const float4*)(y + (size_t)s0 * DDIM))[threadIdx.x];
  float4 b = ((const float4*)(y + (size_t)s1 * DDIM))[threadIdx.x];
  float4 o;
  o.x = p0 * a.x + p1 * b.x;
  o.y = p0 * a.y + p1 * b.y;
  o.z = p0 * a.z + p1 * b.z;
  o.w = p0 * a.w + p1 * b.w;
  ((float4*)(out + (size_t)t * DDIM))[threadIdx.x] = o;
}

extern "C" void kernel_launch(void* const* d_in, const int* in_sizes, int n_in,
                              void* d_out, int out_size, void* d_ws, size_t ws_size,
                              hipStream_t stream) {
  const float* x  = (const float*)d_in[0];
  const float* wg = (const float*)d_in[1];
  const float* w1 = (const float*)d_in[2];
  const float* w3 = (const float*)d_in[3];
  const float* w2 = (const float*)d_in[4];
  float* out = (float*)d_out;
  char* ws = (char*)d_ws;

  size_t off = 0;
  int* hdr = (int*)(ws + off); off += 256;
  int* sel = (int*)(ws + off); off += (size_t)T_TOK * 2 * 4;
  float* prb = (float*)(ws + off); off += (size_t)T_TOK * 2 * 4;
  int* rows = (int*)(ws + off); off += (size_t)T_TOK * 2 * 4;
  int* slot_of = (int*)(ws + off); off += (size_t)T_TOK * 2 * 4;
  int* cnt_blk = (int*)(ws + off); off += (size_t)GBLK * 8 * 4;
  int* blk_off = (int*)(ws + off); off += (size_t)GBLK * 8 * 4;
  unsigned short* xb  = (unsigned short*)(ws + off); off += (size_t)T_TOK * DDIM * 2;
  unsigned short* w1t = (unsigned short*)(ws + off); off += (size_t)EEXP * DDIM * FDIM * 2;
  unsigned short* w3t = (unsigned short*)(ws + off); off += (size_t)EEXP * DDIM * FDIM * 2;
  unsigned short* w2t = (unsigned short*)(ws + off); off += (size_t)EEXP * DDIM * FDIM * 2;
  unsigned short* h   = (unsigned short*)(ws + off); off += (size_t)T_TOK * 2 * FDIM * 2;
  // y overlays w1t+w3t (64 MB, dead after gemm1): [T*2][D] fp32
  float* y = (float*)w1t;

  gate_kernel<<<GBLK, 256, 0, stream>>>(x, wg, xb, sel, prb, cnt_blk);
  transpose_cast3_kernel<<<dim3(32, 32, 24), 256, 0, stream>>>(w1, w3, w2, w1t, w3t, w2t);
  scan_kernel<<<1, 64, 0, stream>>>(cnt_blk, hdr, blk_off);
  build_kernel<<<T_TOK * 2 / 64, 64, 0, stream>>>(sel, blk_off, rows, slot_of);
  gemm1_kernel<<<dim3(FDIM / 128, T_TOK / 128 / 2, EEXP), 512, 0, stream>>>(xb, w1t, w3t, rows, hdr, h);
  gemm2_kernel<<<dim3(DDIM / 256, T_TOK / 128 / 2, EEXP), 512, 0, stream>>>(h, w2t, hdr, y);
  combine_kernel<<<T_TOK, 256, 0, stream>>>(y, slot_of, prb, out);
}

// Round 5
// 560.497 us; speedup vs baseline: 1.5564x; 1.0142x over previous
//
#include <hip/hip_runtime.h>
#include <stdint.h>

#define T_TOK 8192
#define DDIM 1024
#define EEXP 8
#define FDIM 2048
#define GBLK 512   // gate blocks; 16 tokens each

typedef float f32x4 __attribute__((ext_vector_type(4)));
typedef __bf16 bf16x8 __attribute__((ext_vector_type(8)));
typedef unsigned short us8 __attribute__((ext_vector_type(8)));

#define VMCNT(N) asm volatile("s_waitcnt vmcnt(" #N ")" ::: "memory")
// raw s_barrier + scheduler pin: nothing crosses the phase boundary
#define BARS() do { __builtin_amdgcn_s_barrier(); __builtin_amdgcn_sched_barrier(0); } while (0)

__device__ __forceinline__ unsigned short f2bf(float f) {
  union { float f; unsigned int u; } v; v.f = f;
  unsigned int r = (v.u + 0x7fffu + ((v.u >> 16) & 1u)) >> 16;
  return (unsigned short)r;
}

__device__ __forceinline__ void async_cp16(const void* g, void* l) {
  __builtin_amdgcn_global_load_lds(
      (const __attribute__((address_space(1))) unsigned int*)g,
      (__attribute__((address_space(3))) unsigned int*)l, 16, 0, 0);
}

// ---------------- merged vectorized transpose-cast of w1/w3/w2 ----------------
__global__ __launch_bounds__(256) void transpose_cast3_kernel(
    const float* __restrict__ w1, const float* __restrict__ w3, const float* __restrict__ w2,
    unsigned short* __restrict__ w1t, unsigned short* __restrict__ w3t,
    unsigned short* __restrict__ w2t) {
  __shared__ float tile[64][65];
  const int z = blockIdx.z;
  const float* in;
  unsigned short* out;
  int R, C;
  if (z < 16) {
    R = DDIM; C = FDIM;
    const float* s = (z < 8) ? w1 : w3;
    unsigned short* o = (z < 8) ? w1t : w3t;
    in = s + (size_t)(z & 7) * R * C;
    out = o + (size_t)(z & 7) * R * C;
  } else {
    R = FDIM; C = DDIM;
    in = w2 + (size_t)(z & 7) * R * C;
    out = w2t + (size_t)(z & 7) * R * C;
  }
  const int c0 = blockIdx.x * 64;
  const int r0 = blockIdx.y * 64;
  if (c0 >= C || r0 >= R) return;
  const int t = threadIdx.x;
  const int pr = t >> 4;
  const int pc = (t & 15) * 4;
#pragma unroll
  for (int i = 0; i < 4; i++) {
    float4 v = *(const float4*)&in[(size_t)(r0 + pr + i * 16) * C + c0 + pc];
    tile[pr + i * 16][pc + 0] = v.x;
    tile[pr + i * 16][pc + 1] = v.y;
    tile[pr + i * 16][pc + 2] = v.z;
    tile[pr + i * 16][pc + 3] = v.w;
  }
  __syncthreads();
  const int qr = (t & 7) * 8;
  const int qc = t >> 3;
#pragma unroll
  for (int i = 0; i < 2; i++) {
    int cc = qc + i * 32;
    us8 o;
#pragma unroll
    for (int j = 0; j < 8; j++) o[j] = f2bf(tile[qr + j][cc]);
    *(us8*)&out[(size_t)(c0 + cc) * R + r0 + qr] = o;
  }
}

// ---------------- gating + fused x cast: NO global atomics ----------------
__global__ __launch_bounds__(256) void gate_kernel(const float* __restrict__ x,
                                                   const float* __restrict__ wg,
                                                   unsigned short* __restrict__ xb,
                                                   int* __restrict__ sel,
                                                   float* __restrict__ prb,
                                                   int* __restrict__ cnt_blk) {
  __shared__ float wgs[8 * 1024];  // [e][d]
  __shared__ int cnt[8];
  const int tid = threadIdx.x;
  if (tid < 8) cnt[tid] = 0;
  for (int i = tid; i < 8192; i += 256) {
    int d = i >> 3, e = i & 7;
    wgs[e * 1024 + d] = wg[i];
  }
  __syncthreads();
  const int lane = tid & 63;
  const int wv = tid >> 6;
#pragma unroll 1
  for (int tt = 0; tt < 4; tt++) {
    const int t = blockIdx.x * 16 + tt * 4 + wv;
    const float4* xp = (const float4*)(x + (size_t)t * 1024);
    float4 xv[4];
#pragma unroll
    for (int it = 0; it < 4; it++) xv[it] = xp[lane + it * 64];
    float acc[8] = {0.f, 0.f, 0.f, 0.f, 0.f, 0.f, 0.f, 0.f};
    ushort4* xbp = (ushort4*)(xb + (size_t)t * 1024);
#pragma unroll
    for (int it = 0; it < 4; it++) {
      const int d = (lane + it * 64) * 4;
      float4 v = xv[it];
      ushort4 o;
      o.x = f2bf(v.x); o.y = f2bf(v.y); o.z = f2bf(v.z); o.w = f2bf(v.w);
      xbp[lane + it * 64] = o;
#pragma unroll
      for (int e = 0; e < 8; e++)
        acc[e] += v.x * wgs[e * 1024 + d] + v.y * wgs[e * 1024 + d + 1] +
                  v.z * wgs[e * 1024 + d + 2] + v.w * wgs[e * 1024 + d + 3];
    }
#pragma unroll
    for (int e = 0; e < 8; e++) {
      acc[e] += __shfl_xor(acc[e], 32);
      acc[e] += __shfl_xor(acc[e], 16);
      acc[e] += __shfl_xor(acc[e], 8);
      acc[e] += __shfl_xor(acc[e], 4);
      acc[e] += __shfl_xor(acc[e], 2);
      acc[e] += __shfl_xor(acc[e], 1);
    }
    if (lane == 0) {
      int i0 = 0; float v0 = acc[0];
#pragma unroll
      for (int e = 1; e < 8; e++) if (acc[e] > v0) { v0 = acc[e]; i0 = e; }
      int i1 = -1; float v1 = -1e30f;
#pragma unroll
      for (int e = 0; e < 8; e++) if (e != i0 && acc[e] > v1) { v1 = acc[e]; i1 = e; }
      float ex = __expf(v1 - v0);
      float inv = 1.0f / (1.0f + ex);
      sel[t * 2] = i0; sel[t * 2 + 1] = i1;
      prb[t * 2] = inv; prb[t * 2 + 1] = ex * inv;
      atomicAdd(&cnt[i0], 1);   // LDS atomics only
      atomicAdd(&cnt[i1], 1);
    }
  }
  __syncthreads();
  if (tid < 8) cnt_blk[blockIdx.x * 8 + tid] = cnt[tid];
}

// ---------------- scan: totals, expert offsets, per-gate-block offsets -------
__global__ __launch_bounds__(64) void scan_kernel(const int* __restrict__ cnt_blk,
                                                  int* __restrict__ hdr,
                                                  int* __restrict__ blk_off) {
  __shared__ int part[64];
  const int i = threadIdx.x;
  const int e = i & 7, chunk = i >> 3;
  const int CPB = GBLK / 8;
  int s = 0;
  for (int b = 0; b < CPB; b++) s += cnt_blk[(chunk * CPB + b) * 8 + e];
  part[i] = s;
  __syncthreads();
  if (i < 8) {
    int tot = 0;
#pragma unroll
    for (int c = 0; c < 8; c++) tot += part[c * 8 + i];
    hdr[i] = tot;
  }
  __syncthreads();
  if (i == 0) {
    int s2 = 0;
    for (int e2 = 0; e2 < 8; e2++) { hdr[16 + e2] = s2; s2 += hdr[e2]; }
    hdr[24] = s2;
  }
  __syncthreads();
  int running = hdr[16 + e];
  for (int c = 0; c < chunk; c++) running += part[c * 8 + e];
  for (int b = 0; b < CPB; b++) {
    int idx = (chunk * CPB + b) * 8 + e;
    blk_off[idx] = running;
    running += cnt_blk[idx];
  }
}

// ---------------- build: ballot-ranked, deterministic, no atomics ------------
__global__ __launch_bounds__(64) void build_kernel(const int* __restrict__ sel,
                                                   const int* __restrict__ blk_off,
                                                   int* __restrict__ rows,
                                                   int* __restrict__ slot_of) {
  const int lane = threadIdx.x;
  const int i = blockIdx.x * 64 + lane;
  const int gb = i >> 5;
  const int e = sel[i];
  unsigned long long m = 0;
#pragma unroll
  for (int ee = 0; ee < 8; ee++) {
    unsigned long long be = __ballot(e == ee);
    if (ee == e) m = be;
  }
  const unsigned long long half =
      (lane < 32) ? 0x00000000FFFFFFFFull : 0xFFFFFFFF00000000ull;
  const unsigned long long below = (1ull << lane) - 1ull;
  const int rank = __popcll(m & half & below);
  const int pos = blk_off[gb * 8 + e] + rank;
  rows[pos] = i >> 1;
  slot_of[i] = pos;
}

// ======================= 8-phase counted-vmcnt GEMMs (m201 phase body) ======
// Phase body: {ds_read cur-subtile ; stage next ; [vmcnt] ; BAR ; MFMA ; BAR}
// ds_reads issued BEFORE the leading barrier (latency hides under barrier
// wait + other waves' MFMA). Publication rule: a chunk is readable only after
// a vmcnt covering it AND a following barrier (vmcnt is per-wave).
// LDS: [row][64] bf16, phys 16B-slot = logical ^ (row&7).

// ---------------- GEMM1: h = silu(x@w1)*(x@w3) ------------------------------
// 256Mx128N dual-tensor, BK=64. Chunks: A0={q0,q2} A1={q1,q3} B0=w1 B1=w3.
// Reads: ph0:{A0,B0} ph1:{B1} ph2:{A1} ph3:{}. Stage t+1: A0,B0,B1,A1.
// Steady vmcnt 4/4/-/4; tail 2/0/-/-.
__global__ __launch_bounds__(512, 2) void gemm1_kernel(
    const unsigned short* __restrict__ xb,   // [T][D] bf16
    const unsigned short* __restrict__ w1t,  // [E][F][D] bf16
    const unsigned short* __restrict__ w3t,  // [E][F][D] bf16
    const int* __restrict__ rows,
    const int* __restrict__ hdr,
    unsigned short* __restrict__ h)          // [T*2][F] bf16 (slot space)
{
  const int e = blockIdx.z;
  const int count = hdr[e];
  const int m0 = blockIdx.y * 256;
  if (m0 >= count) return;
  const int n0 = blockIdx.x * 128;
  const int sbase = hdr[16 + e];

  __shared__ unsigned short As[2][16384];  // 256 x 64
  __shared__ unsigned short Bs[2][16384];  // [w1:128 | w3:128] x 64

  const int tid = threadIdx.x;
  const int srcoff = ((tid & 7) ^ ((tid >> 3) & 7)) * 8;
  const int rq = tid >> 3;  // 0..63
  const unsigned short* pA[4];
#pragma unroll
  for (int q = 0; q < 4; q++) {
    int m = m0 + q * 64 + rq; if (m > count - 1) m = count - 1;
    pA[q] = xb + (size_t)rows[sbase + m] * DDIM + srcoff;
  }
  const unsigned short* pB[4];
  pB[0] = w1t + ((size_t)e * FDIM + n0 + rq) * DDIM + srcoff;
  pB[1] = w1t + ((size_t)e * FDIM + n0 + 64 + rq) * DDIM + srcoff;
  pB[2] = w3t + ((size_t)e * FDIM + n0 + rq) * DDIM + srcoff;
  pB[3] = w3t + ((size_t)e * FDIM + n0 + 64 + rq) * DDIM + srcoff;
  const int l0 = tid * 8;

  const int wv = tid >> 6;
  const int wr = (wv >> 2) * 128;   // 0 / 128
  const int wn = (wv & 3) * 32;     // 0..96
  const int lane = tid & 63;
  const int lm = lane & 15;
  const int ls = lane >> 4;
  const int coff0 = ((ls) ^ (lm & 7)) * 8;
  const int coff1 = ((4 + ls) ^ (lm & 7)) * 8;

  f32x4 acc1[8][2], acc3[8][2];
#pragma unroll
  for (int i = 0; i < 8; i++)
#pragma unroll
    for (int j = 0; j < 2; j++) {
      acc1[i][j] = f32x4{0.f, 0.f, 0.f, 0.f};
      acc3[i][j] = f32x4{0.f, 0.f, 0.f, 0.f};
    }

  bf16x8 a[8], b1[4], b3[4];

  auto stageA0 = [&](int buf, int kt) {  // rows 0-63 (q0) + 128-191 (q2)
    async_cp16(pA[0] + kt, &As[buf][l0]);
    async_cp16(pA[2] + kt, &As[buf][8192 + l0]);
  };
  auto stageA1 = [&](int buf, int kt) {  // rows 64-127 (q1) + 192-255 (q3)
    async_cp16(pA[1] + kt, &As[buf][4096 + l0]);
    async_cp16(pA[3] + kt, &As[buf][12288 + l0]);
  };
  auto stageB0 = [&](int buf, int kt) {  // w1 rows 0-127
    async_cp16(pB[0] + kt, &Bs[buf][l0]);
    async_cp16(pB[1] + kt, &Bs[buf][4096 + l0]);
  };
  auto stageB1 = [&](int buf, int kt) {  // w3 rows 0-127
    async_cp16(pB[2] + kt, &Bs[buf][8192 + l0]);
    async_cp16(pB[3] + kt, &Bs[buf][12288 + l0]);
  };
  auto rdA = [&](int cur, int mh) {
#pragma unroll
    for (int i = 0; i < 4; i++) {
      const unsigned short* rp = &As[cur][(wr + mh * 64 + i * 16 + lm) * 64];
      a[i * 2 + 0] = *(const bf16x8*)(rp + coff0);
      a[i * 2 + 1] = *(const bf16x8*)(rp + coff1);
    }
  };
  auto rdB = [&](int cur, int half, bf16x8* bb) {
#pragma unroll
    for (int j = 0; j < 2; j++) {
      const unsigned short* rp = &Bs[cur][(half * 128 + wn + j * 16 + lm) * 64];
      bb[j * 2 + 0] = *(const bf16x8*)(rp + coff0);
      bb[j * 2 + 1] = *(const bf16x8*)(rp + coff1);
    }
  };
  auto mm = [&](f32x4 (*acc)[2], int mh, bf16x8* bb) {
    __builtin_amdgcn_s_setprio(1);
#pragma unroll
    for (int i = 0; i < 4; i++)
#pragma unroll
      for (int j = 0; j < 2; j++) {
        f32x4 c = acc[mh * 4 + i][j];
        c = __builtin_amdgcn_mfma_f32_16x16x32_bf16(a[i * 2 + 0], bb[j * 2 + 0], c, 0, 0, 0);
        c = __builtin_amdgcn_mfma_f32_16x16x32_bf16(a[i * 2 + 1], bb[j * 2 + 1], c, 0, 0, 0);
        acc[mh * 4 + i][j] = c;
      }
    __builtin_amdgcn_s_setprio(0);
  };

  // prologue: stage tile 0; publish {A0,B0}(0)
  stageA0(0, 0); stageB0(0, 0); stageB1(0, 0); stageA1(0, 0);
  VMCNT(4); BARS();

  for (int t = 0; t < 15; ++t) {
    const int cur = t & 1, nxt = cur ^ 1;
    const int kt = (t + 1) * 64;
    // ph0: publish B1(t)
    rdA(cur, 0); rdB(cur, 0, b1); stageA0(nxt, kt); VMCNT(4); BARS();
    mm(acc1, 0, b1); BARS();
    // ph1: publish A1(t)
    rdB(cur, 1, b3); stageB0(nxt, kt); VMCNT(4); BARS();
    mm(acc3, 0, b3); BARS();
    // ph2
    rdA(cur, 1); stageB1(nxt, kt); BARS();
    mm(acc1, 1, b1); BARS();
    // ph3: publish {A0,B0}(t+1)
    stageA1(nxt, kt); VMCNT(4); BARS();
    mm(acc3, 1, b3); BARS();
  }
  {  // tail t=15 (cur=1), no staging; entry queue {B1,A1}=4
    rdA(1, 0); rdB(1, 0, b1); VMCNT(2); BARS();
    mm(acc1, 0, b1); BARS();
    rdB(1, 1, b3); VMCNT(0); BARS();
    mm(acc3, 0, b3); BARS();
    rdA(1, 1); BARS();
    mm(acc1, 1, b1); BARS();
    mm(acc3, 1, b3);
  }

#pragma unroll
  for (int i = 0; i < 8; i++) {
#pragma unroll
    for (int r = 0; r < 4; r++) {
      int mg = m0 + wr + i * 16 + ls * 4 + r;
      if (mg < count) {
        unsigned short* hp = h + (size_t)(sbase + mg) * FDIM + n0 + wn + lm;
#pragma unroll
        for (int j = 0; j < 2; j++) {
          float v1 = acc1[i][j][r];
          float v3 = acc3[i][j][r];
          float hv = (v1 / (1.0f + __expf(-v1))) * v3;
          hp[j * 16] = f2bf(hv);
        }
      }
    }
  }
}

// ---------------- GEMM2: y[slot] = h[slot] @ w2 ------------------------------
// 256Mx256N, BK=64. Reads: ph0:{A0,B(all)} ph1:{same,kk1} ph2:{A1} ph3:{A1,kk1}.
// Stage t+1: B0,B1,A0,A1. Steady vmcnt -/4/-/2; tail -/0/-/-.
__global__ __launch_bounds__(512, 2) void gemm2_kernel(
    const unsigned short* __restrict__ h,    // [T*2][F] bf16
    const unsigned short* __restrict__ w2t,  // [E][D][F] bf16
    const int* __restrict__ hdr,
    float* __restrict__ y)                   // [T*2][D] fp32 (slot space)
{
  const int e = blockIdx.z;
  const int count = hdr[e];
  const int m0 = blockIdx.y * 256;
  if (m0 >= count) return;
  const int n0 = blockIdx.x * 256;
  const int sbase = hdr[16 + e];

  __shared__ unsigned short As[2][16384];  // 256 x 64
  __shared__ unsigned short Bs[2][16384];  // 256 x 64

  const int tid = threadIdx.x;
  const int srcoff = ((tid & 7) ^ ((tid >> 3) & 7)) * 8;
  const int rq = tid >> 3;
  const unsigned short* pA[4];
#pragma unroll
  for (int q = 0; q < 4; q++) {
    int m = m0 + q * 64 + rq; if (m > count - 1) m = count - 1;
    pA[q] = h + (size_t)(sbase + m) * FDIM + srcoff;
  }
  const unsigned short* pB[4];
#pragma unroll
  for (int q = 0; q < 4; q++)
    pB[q] = w2t + ((size_t)e * DDIM + n0 + q * 64 + rq) * FDIM + srcoff;
  const int l0 = tid * 8;

  const int wv = tid >> 6;
  const int wr = (wv >> 2) * 128;
  const int wn = (wv & 3) * 64;
  const int lane = tid & 63;
  const int lm = lane & 15;
  const int ls = lane >> 4;
  const int coff0 = ((ls) ^ (lm & 7)) * 8;
  const int coff1 = ((4 + ls) ^ (lm & 7)) * 8;

  f32x4 acc[8][4];
#pragma unroll
  for (int i = 0; i < 8; i++)
#pragma unroll
    for (int j = 0; j < 4; j++) acc[i][j] = f32x4{0.f, 0.f, 0.f, 0.f};

  bf16x8 a[8], b[8];

  auto stageA0 = [&](int buf, int kt) {  // rows 0-63 (q0) + 128-191 (q2)
    async_cp16(pA[0] + kt, &As[buf][l0]);
    async_cp16(pA[2] + kt, &As[buf][8192 + l0]);
  };
  auto stageA1 = [&](int buf, int kt) {  // rows 64-127 (q1) + 192-255 (q3)
    async_cp16(pA[1] + kt, &As[buf][4096 + l0]);
    async_cp16(pA[3] + kt, &As[buf][12288 + l0]);
  };
  auto stageB0 = [&](int buf, int kt) {
    async_cp16(pB[0] + kt, &Bs[buf][l0]);
    async_cp16(pB[1] + kt, &Bs[buf][4096 + l0]);
  };
  auto stageB1 = [&](int buf, int kt) {
    async_cp16(pB[2] + kt, &Bs[buf][8192 + l0]);
    async_cp16(pB[3] + kt, &Bs[buf][12288 + l0]);
  };
  auto rdA2 = [&](int cur, int mh, int kk) {
#pragma unroll
    for (int i = 0; i < 4; i++) {
      const unsigned short* rp = &As[cur][(wr + mh * 64 + i * 16 + lm) * 64];
      a[kk * 4 + i] = *(const bf16x8*)(rp + (kk ? coff1 : coff0));
    }
  };
  auto rdB2 = [&](int cur, int kk) {
#pragma unroll
    for (int j = 0; j < 4; j++) {
      const unsigned short* rp = &Bs[cur][(wn + j * 16 + lm) * 64];
      b[kk * 4 + j] = *(const bf16x8*)(rp + (kk ? coff1 : coff0));
    }
  };
  auto mm2 = [&](int mh, int kk) {
    __builtin_amdgcn_s_setprio(1);
#pragma unroll
    for (int i = 0; i < 4; i++)
#pragma unroll
      for (int j = 0; j < 4; j++)
        acc[mh * 4 + i][j] =
            __builtin_amdgcn_mfma_f32_16x16x32_bf16(a[kk * 4 + i], b[kk * 4 + j],
                                                    acc[mh * 4 + i][j], 0, 0, 0);
    __builtin_amdgcn_s_setprio(0);
  };

  // prologue: stage tile 0; publish {B0,B1,A0}(0)
  stageB0(0, 0); stageB1(0, 0); stageA0(0, 0); stageA1(0, 0);
  VMCNT(2); BARS();

  for (int t = 0; t < 31; ++t) {
    const int cur = t & 1, nxt = cur ^ 1;
    const int kt = (t + 1) * 64;
    // ph0
    rdA2(cur, 0, 0); rdB2(cur, 0); stageB0(nxt, kt); BARS();
    mm2(0, 0); BARS();
    // ph1: publish A1(t)
    rdA2(cur, 0, 1); rdB2(cur, 1); stageB1(nxt, kt); VMCNT(4); BARS();
    mm2(0, 1); BARS();
    // ph2
    rdA2(cur, 1, 0); stageA0(nxt, kt); BARS();
    mm2(1, 0); BARS();
    // ph3: publish {B0,B1,A0}(t+1)
    rdA2(cur, 1, 1); stageA1(nxt, kt); VMCNT(2); BARS();
    mm2(1, 1); BARS();
  }
  {  // tail t=31 (cur=1), no staging; entry queue {A1}=2
    rdA2(1, 0, 0); rdB2(1, 0); BARS();
    mm2(0, 0); BARS();
    rdA2(1, 0, 1); rdB2(1, 1); VMCNT(0); BARS();
    mm2(0, 1); BARS();
    rdA2(1, 1, 0); BARS();
    mm2(1, 0); BARS();
    rdA2(1, 1, 1); BARS();
    mm2(1, 1);
  }

#pragma unroll
  for (int i = 0; i < 8; i++) {
#pragma unroll
    for (int r = 0; r < 4; r++) {
      int mg = m0 + wr + i * 16 + ls * 4 + r;
      if (mg < count) {
        float* yp = y + (size_t)(sbase + mg) * DDIM + n0 + wn + lm;
#pragma unroll
        for (int j = 0; j < 4; j++) yp[j * 16] = acc[i][j][r];
      }
    }
  }
}

// ---------------- combine: out[t] = p0*y[s0] + p1*y[s1] ----------------
__global__ __launch_bounds__(256) void combine_kernel(const float* __restrict__ y,
                                                      const int* __restrict__ slot_of,
                                                      const float* __restrict__ prb,
                                                      float* __restrict__ out) {
  int t = blockIdx.x;
  int s0 = slot_of[t * 2], s1 = slot_of[t * 2 + 1];
  float p0 = prb[t * 2], p1 = prb[t * 2 + 1];
  float4 a = ((const float4*)(y + (size_t)s0 * DDIM))[threadIdx.x];
  float4 b = ((const float4*)(y + (size_t)s1 * DDIM))[threadIdx.x];
  float4 o;
  o.x = p0 * a.x + p1 * b.x;
  o.y = p0 * a.y + p1 * b.y;
  o.z = p0 * a.z + p1 * b.z;
  o.w = p0 * a.w + p1 * b.w;
  ((float4*)(out + (size_t)t * DDIM))[threadIdx.x] = o;
}

extern "C" void kernel_launch(void* const* d_in, const int* in_sizes, int n_in,
                              void* d_out, int out_size, void* d_ws, size_t ws_size,
                              hipStream_t stream) {
  const float* x  = (const float*)d_in[0];
  const float* wg = (const float*)d_in[1];
  const float* w1 = (const float*)d_in[2];
  const float* w3 = (const float*)d_in[3];
  const float* w2 = (const float*)d_in[4];
  float* out = (float*)d_out;
  char* ws = (char*)d_ws;

  size_t off = 0;
  int* hdr = (int*)(ws + off); off += 256;
  int* sel = (int*)(ws + off); off += (size_t)T_TOK * 2 * 4;
  float* prb = (float*)(ws + off); off += (size_t)T_TOK * 2 * 4;
  int* rows = (int*)(ws + off); off += (size_t)T_TOK * 2 * 4;
  int* slot_of = (int*)(ws + off); off += (size_t)T_TOK * 2 * 4;
  int* cnt_blk = (int*)(ws + off); off += (size_t)GBLK * 8 * 4;
  int* blk_off = (int*)(ws + off); off += (size_t)GBLK * 8 * 4;
  unsigned short* xb  = (unsigned short*)(ws + off); off += (size_t)T_TOK * DDIM * 2;
  unsigned short* w1t = (unsigned short*)(ws + off); off += (size_t)EEXP * DDIM * FDIM * 2;
  unsigned short* w3t = (unsigned short*)(ws + off); off += (size_t)EEXP * DDIM * FDIM * 2;
  unsigned short* w2t = (unsigned short*)(ws + off); off += (size_t)EEXP * DDIM * FDIM * 2;
  unsigned short* h   = (unsigned short*)(ws + off); off += (size_t)T_TOK * 2 * FDIM * 2;
  // y overlays w1t+w3t (64 MB, dead after gemm1): [T*2][D] fp32
  float* y = (float*)w1t;

  gate_kernel<<<GBLK, 256, 0, stream>>>(x, wg, xb, sel, prb, cnt_blk);
  transpose_cast3_kernel<<<dim3(32, 32, 24), 256, 0, stream>>>(w1, w3, w2, w1t, w3t, w2t);
  scan_kernel<<<1, 64, 0, stream>>>(cnt_blk, hdr, blk_off);
  build_kernel<<<T_TOK * 2 / 64, 64, 0, stream>>>(sel, blk_off, rows, slot_of);
  gemm1_kernel<<<dim3(FDIM / 128, T_TOK / 128 / 2, EEXP), 512, 0, stream>>>(xb, w1t, w3t, rows, hdr, h);
  gemm2_kernel<<<dim3(DDIM / 256, T_TOK / 128 / 2, EEXP), 512, 0, stream>>>(h, w2t, hdr, y);
  combine_kernel<<<T_TOK, 256, 0, stream>>>(y, slot_of, prb, out);
}

// Round 6
// 542.417 us; speedup vs baseline: 1.6083x; 1.0333x over previous
//
#include <hip/hip_runtime.h>
#include <stdint.h>

#define T_TOK 8192
#define DDIM 1024
#define EEXP 8
#define FDIM 2048
#define GBLK 512   // gate blocks; 16 tokens each

typedef float f32x4 __attribute__((ext_vector_type(4)));
typedef __bf16 bf16x8 __attribute__((ext_vector_type(8)));
typedef unsigned short us8 __attribute__((ext_vector_type(8)));

#define VMCNT(N) asm volatile("s_waitcnt vmcnt(" #N ")" ::: "memory")
#define BAR() __builtin_amdgcn_s_barrier()

__device__ __forceinline__ unsigned short f2bf(float f) {
  union { float f; unsigned int u; } v; v.f = f;
  unsigned int r = (v.u + 0x7fffu + ((v.u >> 16) & 1u)) >> 16;
  return (unsigned short)r;
}

__device__ __forceinline__ void async_cp16(const void* g, void* l) {
  __builtin_amdgcn_global_load_lds(
      (const __attribute__((address_space(1))) unsigned int*)g,
      (__attribute__((address_space(3))) unsigned int*)l, 16, 0, 0);
}

// ---------------- merged vectorized transpose-cast of w1/w3/w2 ----------------
__global__ __launch_bounds__(256) void transpose_cast3_kernel(
    const float* __restrict__ w1, const float* __restrict__ w3, const float* __restrict__ w2,
    unsigned short* __restrict__ w1t, unsigned short* __restrict__ w3t,
    unsigned short* __restrict__ w2t) {
  __shared__ float tile[64][65];
  const int z = blockIdx.z;
  const float* in;
  unsigned short* out;
  int R, C;
  if (z < 16) {
    R = DDIM; C = FDIM;
    const float* s = (z < 8) ? w1 : w3;
    unsigned short* o = (z < 8) ? w1t : w3t;
    in = s + (size_t)(z & 7) * R * C;
    out = o + (size_t)(z & 7) * R * C;
  } else {
    R = FDIM; C = DDIM;
    in = w2 + (size_t)(z & 7) * R * C;
    out = w2t + (size_t)(z & 7) * R * C;
  }
  const int c0 = blockIdx.x * 64;
  const int r0 = blockIdx.y * 64;
  if (c0 >= C || r0 >= R) return;
  const int t = threadIdx.x;
  const int pr = t >> 4;
  const int pc = (t & 15) * 4;
#pragma unroll
  for (int i = 0; i < 4; i++) {
    float4 v = *(const float4*)&in[(size_t)(r0 + pr + i * 16) * C + c0 + pc];
    tile[pr + i * 16][pc + 0] = v.x;
    tile[pr + i * 16][pc + 1] = v.y;
    tile[pr + i * 16][pc + 2] = v.z;
    tile[pr + i * 16][pc + 3] = v.w;
  }
  __syncthreads();
  const int qr = (t & 7) * 8;
  const int qc = t >> 3;
#pragma unroll
  for (int i = 0; i < 2; i++) {
    int cc = qc + i * 32;
    us8 o;
#pragma unroll
    for (int j = 0; j < 8; j++) o[j] = f2bf(tile[qr + j][cc]);
    *(us8*)&out[(size_t)(c0 + cc) * R + r0 + qr] = o;
  }
}

// ---------------- gating + fused x cast: NO global atomics ----------------
__global__ __launch_bounds__(256) void gate_kernel(const float* __restrict__ x,
                                                   const float* __restrict__ wg,
                                                   unsigned short* __restrict__ xb,
                                                   int* __restrict__ sel,
                                                   float* __restrict__ prb,
                                                   int* __restrict__ cnt_blk) {
  __shared__ float wgs[8 * 1024];  // [e][d]
  __shared__ int cnt[8];
  const int tid = threadIdx.x;
  if (tid < 8) cnt[tid] = 0;
  for (int i = tid; i < 8192; i += 256) {
    int d = i >> 3, e = i & 7;
    wgs[e * 1024 + d] = wg[i];
  }
  __syncthreads();
  const int lane = tid & 63;
  const int wv = tid >> 6;
#pragma unroll 1
  for (int tt = 0; tt < 4; tt++) {
    const int t = blockIdx.x * 16 + tt * 4 + wv;
    const float4* xp = (const float4*)(x + (size_t)t * 1024);
    float4 xv[4];
#pragma unroll
    for (int it = 0; it < 4; it++) xv[it] = xp[lane + it * 64];
    float acc[8] = {0.f, 0.f, 0.f, 0.f, 0.f, 0.f, 0.f, 0.f};
    ushort4* xbp = (ushort4*)(xb + (size_t)t * 1024);
#pragma unroll
    for (int it = 0; it < 4; it++) {
      const int d = (lane + it * 64) * 4;
      float4 v = xv[it];
      ushort4 o;
      o.x = f2bf(v.x); o.y = f2bf(v.y); o.z = f2bf(v.z); o.w = f2bf(v.w);
      xbp[lane + it * 64] = o;
#pragma unroll
      for (int e = 0; e < 8; e++)
        acc[e] += v.x * wgs[e * 1024 + d] + v.y * wgs[e * 1024 + d + 1] +
                  v.z * wgs[e * 1024 + d + 2] + v.w * wgs[e * 1024 + d + 3];
    }
#pragma unroll
    for (int e = 0; e < 8; e++) {
      acc[e] += __shfl_xor(acc[e], 32);
      acc[e] += __shfl_xor(acc[e], 16);
      acc[e] += __shfl_xor(acc[e], 8);
      acc[e] += __shfl_xor(acc[e], 4);
      acc[e] += __shfl_xor(acc[e], 2);
      acc[e] += __shfl_xor(acc[e], 1);
    }
    if (lane == 0) {
      int i0 = 0; float v0 = acc[0];
#pragma unroll
      for (int e = 1; e < 8; e++) if (acc[e] > v0) { v0 = acc[e]; i0 = e; }
      int i1 = -1; float v1 = -1e30f;
#pragma unroll
      for (int e = 0; e < 8; e++) if (e != i0 && acc[e] > v1) { v1 = acc[e]; i1 = e; }
      float ex = __expf(v1 - v0);
      float inv = 1.0f / (1.0f + ex);
      sel[t * 2] = i0; sel[t * 2 + 1] = i1;
      prb[t * 2] = inv; prb[t * 2 + 1] = ex * inv;
      atomicAdd(&cnt[i0], 1);   // LDS atomics only
      atomicAdd(&cnt[i1], 1);
    }
  }
  __syncthreads();
  if (tid < 8) cnt_blk[blockIdx.x * 8 + tid] = cnt[tid];
}

// ---------------- scan: totals, expert offsets, per-gate-block offsets -------
__global__ __launch_bounds__(64) void scan_kernel(const int* __restrict__ cnt_blk,
                                                  int* __restrict__ hdr,
                                                  int* __restrict__ blk_off) {
  __shared__ int part[64];
  const int i = threadIdx.x;
  const int e = i & 7, chunk = i >> 3;
  const int CPB = GBLK / 8;
  int s = 0;
  for (int b = 0; b < CPB; b++) s += cnt_blk[(chunk * CPB + b) * 8 + e];
  part[i] = s;
  __syncthreads();
  if (i < 8) {
    int tot = 0;
#pragma unroll
    for (int c = 0; c < 8; c++) tot += part[c * 8 + i];
    hdr[i] = tot;
  }
  __syncthreads();
  if (i == 0) {
    int s2 = 0;
    for (int e2 = 0; e2 < 8; e2++) { hdr[16 + e2] = s2; s2 += hdr[e2]; }
    hdr[24] = s2;
  }
  __syncthreads();
  int running = hdr[16 + e];
  for (int c = 0; c < chunk; c++) running += part[c * 8 + e];
  for (int b = 0; b < CPB; b++) {
    int idx = (chunk * CPB + b) * 8 + e;
    blk_off[idx] = running;
    running += cnt_blk[idx];
  }
}

// ---------------- build: ballot-ranked, deterministic, no atomics ------------
__global__ __launch_bounds__(64) void build_kernel(const int* __restrict__ sel,
                                                   const int* __restrict__ blk_off,
                                                   int* __restrict__ rows,
                                                   int* __restrict__ slot_of) {
  const int lane = threadIdx.x;
  const int i = blockIdx.x * 64 + lane;
  const int gb = i >> 5;
  const int e = sel[i];
  unsigned long long m = 0;
#pragma unroll
  for (int ee = 0; ee < 8; ee++) {
    unsigned long long be = __ballot(e == ee);
    if (ee == e) m = be;
  }
  const unsigned long long half =
      (lane < 32) ? 0x00000000FFFFFFFFull : 0xFFFFFFFF00000000ull;
  const unsigned long long below = (1ull << lane) - 1ull;
  const int rank = __popcll(m & half & below);
  const int pos = blk_off[gb * 8 + e] + rank;
  rows[pos] = i >> 1;
  slot_of[i] = pos;
}

// ============ 8-phase counted-vmcnt GEMMs — hybrid phase body ===============
// Phase = { ds_read(cur subtile) ; stage(nxt chunk) ; [VMCNT] ; s_barrier ;
//           setprio(1) MFMA setprio(0) }.
// Reads issue BEFORE the wait (latency hides under vmcnt+barrier stall);
// ONE barrier per phase; NO sched_barrier (r5 lesson: pins kill compiler ILP).
// Publication rule: read of chunk X follows the vmcnt(+bar) that covers X;
// the "memory"-clobbered VMCNT asm blocks illegal hoisting. WAR on dbuf safe:
// reads are consumed by MFMA (lgkmcnt) >=3 barriers before restage.
// LDS: [row][64] bf16, phys 16B-slot = logical ^ (row&7).

// ---------------- GEMM1: h = silu(x@w1)*(x@w3) ------------------------------
// 256Mx128N dual-tensor, BK=64. Chunks: A0={q0,q2} A1={q1,q3} B0=w1 B1=w3.
// Reads: ph0:{A0,B0} ph1:{B1} ph2:{A1} ph3:{}. Stage t+1: A0,B0,B1,A1.
// Steady vmcnt 4/4/-/4; prologue 4; tail 0 once.
__global__ __launch_bounds__(512, 2) void gemm1_kernel(
    const unsigned short* __restrict__ xb,   // [T][D] bf16
    const unsigned short* __restrict__ w1t,  // [E][F][D] bf16
    const unsigned short* __restrict__ w3t,  // [E][F][D] bf16
    const int* __restrict__ rows,
    const int* __restrict__ hdr,
    unsigned short* __restrict__ h)          // [T*2][F] bf16 (slot space)
{
  const int e = blockIdx.z;
  const int count = hdr[e];
  const int m0 = blockIdx.y * 256;
  if (m0 >= count) return;
  const int n0 = blockIdx.x * 128;
  const int sbase = hdr[16 + e];

  __shared__ unsigned short As[2][16384];  // 256 x 64
  __shared__ unsigned short Bs[2][16384];  // [w1:128 | w3:128] x 64

  const int tid = threadIdx.x;
  const int srcoff = ((tid & 7) ^ ((tid >> 3) & 7)) * 8;
  const int rq = tid >> 3;  // 0..63
  const unsigned short* pA[4];
#pragma unroll
  for (int q = 0; q < 4; q++) {
    int m = m0 + q * 64 + rq; if (m > count - 1) m = count - 1;
    pA[q] = xb + (size_t)rows[sbase + m] * DDIM + srcoff;
  }
  const unsigned short* pB[4];
  pB[0] = w1t + ((size_t)e * FDIM + n0 + rq) * DDIM + srcoff;
  pB[1] = w1t + ((size_t)e * FDIM + n0 + 64 + rq) * DDIM + srcoff;
  pB[2] = w3t + ((size_t)e * FDIM + n0 + rq) * DDIM + srcoff;
  pB[3] = w3t + ((size_t)e * FDIM + n0 + 64 + rq) * DDIM + srcoff;
  const int l0 = tid * 8;

  const int wv = tid >> 6;
  const int wr = (wv >> 2) * 128;   // 0 / 128
  const int wn = (wv & 3) * 32;     // 0..96
  const int lane = tid & 63;
  const int lm = lane & 15;
  const int ls = lane >> 4;
  const int coff0 = ((ls) ^ (lm & 7)) * 8;
  const int coff1 = ((4 + ls) ^ (lm & 7)) * 8;

  f32x4 acc1[8][2], acc3[8][2];
#pragma unroll
  for (int i = 0; i < 8; i++)
#pragma unroll
    for (int j = 0; j < 2; j++) {
      acc1[i][j] = f32x4{0.f, 0.f, 0.f, 0.f};
      acc3[i][j] = f32x4{0.f, 0.f, 0.f, 0.f};
    }

  bf16x8 a[8], b1[4], b3[4];

  auto stageA0 = [&](int buf, int kt) {  // rows 0-63 (q0) + 128-191 (q2)
    async_cp16(pA[0] + kt, &As[buf][l0]);
    async_cp16(pA[2] + kt, &As[buf][8192 + l0]);
  };
  auto stageA1 = [&](int buf, int kt) {  // rows 64-127 (q1) + 192-255 (q3)
    async_cp16(pA[1] + kt, &As[buf][4096 + l0]);
    async_cp16(pA[3] + kt, &As[buf][12288 + l0]);
  };
  auto stageB0 = [&](int buf, int kt) {  // w1 rows 0-127
    async_cp16(pB[0] + kt, &Bs[buf][l0]);
    async_cp16(pB[1] + kt, &Bs[buf][4096 + l0]);
  };
  auto stageB1 = [&](int buf, int kt) {  // w3 rows 0-127
    async_cp16(pB[2] + kt, &Bs[buf][8192 + l0]);
    async_cp16(pB[3] + kt, &Bs[buf][12288 + l0]);
  };
  auto rdA = [&](int cur, int mh) {
#pragma unroll
    for (int i = 0; i < 4; i++) {
      const unsigned short* rp = &As[cur][(wr + mh * 64 + i * 16 + lm) * 64];
      a[i * 2 + 0] = *(const bf16x8*)(rp + coff0);
      a[i * 2 + 1] = *(const bf16x8*)(rp + coff1);
    }
  };
  auto rdB = [&](int cur, int half, bf16x8* bb) {
#pragma unroll
    for (int j = 0; j < 2; j++) {
      const unsigned short* rp = &Bs[cur][(half * 128 + wn + j * 16 + lm) * 64];
      bb[j * 2 + 0] = *(const bf16x8*)(rp + coff0);
      bb[j * 2 + 1] = *(const bf16x8*)(rp + coff1);
    }
  };
  auto mm = [&](f32x4 (*acc)[2], int mh, bf16x8* bb) {
    __builtin_amdgcn_s_setprio(1);
#pragma unroll
    for (int i = 0; i < 4; i++)
#pragma unroll
      for (int j = 0; j < 2; j++) {
        f32x4 c = acc[mh * 4 + i][j];
        c = __builtin_amdgcn_mfma_f32_16x16x32_bf16(a[i * 2 + 0], bb[j * 2 + 0], c, 0, 0, 0);
        c = __builtin_amdgcn_mfma_f32_16x16x32_bf16(a[i * 2 + 1], bb[j * 2 + 1], c, 0, 0, 0);
        acc[mh * 4 + i][j] = c;
      }
    __builtin_amdgcn_s_setprio(0);
  };

  // prologue: stage tile 0; publish {A0,B0}(0)
  stageA0(0, 0); stageB0(0, 0); stageB1(0, 0); stageA1(0, 0);
  VMCNT(4); BAR();

  for (int t = 0; t < 15; ++t) {
    const int cur = t & 1, nxt = cur ^ 1;
    const int kt = (t + 1) * 64;
    // ph0: publish B1(t)
    rdA(cur, 0); rdB(cur, 0, b1); stageA0(nxt, kt); VMCNT(4); BAR();
    mm(acc1, 0, b1);
    // ph1: publish A1(t)
    rdB(cur, 1, b3); stageB0(nxt, kt); VMCNT(4); BAR();
    mm(acc3, 0, b3);
    // ph2: no publication
    rdA(cur, 1); stageB1(nxt, kt); BAR();
    mm(acc1, 1, b1);
    // ph3: publish {A0,B0}(t+1)
    stageA1(nxt, kt); VMCNT(4); BAR();
    mm(acc3, 1, b3);
  }
  {  // tail t=15 (cur=1), no staging; entry queue {B1,A1}=4
    rdA(1, 0); rdB(1, 0, b1); VMCNT(0); BAR();
    mm(acc1, 0, b1);
    rdB(1, 1, b3); mm(acc3, 0, b3);
    rdA(1, 1); mm(acc1, 1, b1);
    mm(acc3, 1, b3);
  }

#pragma unroll
  for (int i = 0; i < 8; i++) {
#pragma unroll
    for (int r = 0; r < 4; r++) {
      int mg = m0 + wr + i * 16 + ls * 4 + r;
      if (mg < count) {
        unsigned short* hp = h + (size_t)(sbase + mg) * FDIM + n0 + wn + lm;
#pragma unroll
        for (int j = 0; j < 2; j++) {
          float v1 = acc1[i][j][r];
          float v3 = acc3[i][j][r];
          float hv = (v1 / (1.0f + __expf(-v1))) * v3;
          hp[j * 16] = f2bf(hv);
        }
      }
    }
  }
}

// ---------------- GEMM2: y[slot] = h[slot] @ w2 ------------------------------
// 256Mx256N, BK=64. Reads: ph0:{A0,B kk0} ph1:{A0,B kk1} ph2:{A1 kk0} ph3:{A1 kk1}.
// Stage t+1: B0,B1,A0,A1. Steady vmcnt -/4/-/2; prologue 2; tail 0 once.
__global__ __launch_bounds__(512, 2) void gemm2_kernel(
    const unsigned short* __restrict__ h,    // [T*2][F] bf16
    const unsigned short* __restrict__ w2t,  // [E][D][F] bf16
    const int* __restrict__ hdr,
    float* __restrict__ y)                   // [T*2][D] fp32 (slot space)
{
  const int e = blockIdx.z;
  const int count = hdr[e];
  const int m0 = blockIdx.y * 256;
  if (m0 >= count) return;
  const int n0 = blockIdx.x * 256;
  const int sbase = hdr[16 + e];

  __shared__ unsigned short As[2][16384];  // 256 x 64
  __shared__ unsigned short Bs[2][16384];  // 256 x 64

  const int tid = threadIdx.x;
  const int srcoff = ((tid & 7) ^ ((tid >> 3) & 7)) * 8;
  const int rq = tid >> 3;
  const unsigned short* pA[4];
#pragma unroll
  for (int q = 0; q < 4; q++) {
    int m = m0 + q * 64 + rq; if (m > count - 1) m = count - 1;
    pA[q] = h + (size_t)(sbase + m) * FDIM + srcoff;
  }
  const unsigned short* pB[4];
#pragma unroll
  for (int q = 0; q < 4; q++)
    pB[q] = w2t + ((size_t)e * DDIM + n0 + q * 64 + rq) * FDIM + srcoff;
  const int l0 = tid * 8;

  const int wv = tid >> 6;
  const int wr = (wv >> 2) * 128;
  const int wn = (wv & 3) * 64;
  const int lane = tid & 63;
  const int lm = lane & 15;
  const int ls = lane >> 4;
  const int coff0 = ((ls) ^ (lm & 7)) * 8;
  const int coff1 = ((4 + ls) ^ (lm & 7)) * 8;

  f32x4 acc[8][4];
#pragma unroll
  for (int i = 0; i < 8; i++)
#pragma unroll
    for (int j = 0; j < 4; j++) acc[i][j] = f32x4{0.f, 0.f, 0.f, 0.f};

  bf16x8 a[8], b[8];

  auto stageA0 = [&](int buf, int kt) {  // rows 0-63 (q0) + 128-191 (q2)
    async_cp16(pA[0] + kt, &As[buf][l0]);
    async_cp16(pA[2] + kt, &As[buf][8192 + l0]);
  };
  auto stageA1 = [&](int buf, int kt) {  // rows 64-127 (q1) + 192-255 (q3)
    async_cp16(pA[1] + kt, &As[buf][4096 + l0]);
    async_cp16(pA[3] + kt, &As[buf][12288 + l0]);
  };
  auto stageB0 = [&](int buf, int kt) {
    async_cp16(pB[0] + kt, &Bs[buf][l0]);
    async_cp16(pB[1] + kt, &Bs[buf][4096 + l0]);
  };
  auto stageB1 = [&](int buf, int kt) {
    async_cp16(pB[2] + kt, &Bs[buf][8192 + l0]);
    async_cp16(pB[3] + kt, &Bs[buf][12288 + l0]);
  };
  auto rdA2 = [&](int cur, int mh, int kk) {
#pragma unroll
    for (int i = 0; i < 4; i++) {
      const unsigned short* rp = &As[cur][(wr + mh * 64 + i * 16 + lm) * 64];
      a[kk * 4 + i] = *(const bf16x8*)(rp + (kk ? coff1 : coff0));
    }
  };
  auto rdB2 = [&](int cur, int kk) {
#pragma unroll
    for (int j = 0; j < 4; j++) {
      const unsigned short* rp = &Bs[cur][(wn + j * 16 + lm) * 64];
      b[kk * 4 + j] = *(const bf16x8*)(rp + (kk ? coff1 : coff0));
    }
  };
  auto mm2 = [&](int mh, int kk) {
    __builtin_amdgcn_s_setprio(1);
#pragma unroll
    for (int i = 0; i < 4; i++)
#pragma unroll
      for (int j = 0; j < 4; j++)
        acc[mh * 4 + i][j] =
            __builtin_amdgcn_mfma_f32_16x16x32_bf16(a[kk * 4 + i], b[kk * 4 + j],
                                                    acc[mh * 4 + i][j], 0, 0, 0);
    __builtin_amdgcn_s_setprio(0);
  };

  // prologue: stage tile 0; publish {B0,B1,A0}(0)
  stageB0(0, 0); stageB1(0, 0); stageA0(0, 0); stageA1(0, 0);
  VMCNT(2); BAR();

  for (int t = 0; t < 31; ++t) {
    const int cur = t & 1, nxt = cur ^ 1;
    const int kt = (t + 1) * 64;
    // ph0: no publication (all inputs published at ph3(t-1))
    rdA2(cur, 0, 0); rdB2(cur, 0); stageB0(nxt, kt); BAR();
    mm2(0, 0);
    // ph1: publish A1(t)
    rdA2(cur, 0, 1); rdB2(cur, 1); stageB1(nxt, kt); VMCNT(4); BAR();
    mm2(0, 1);
    // ph2: no publication
    rdA2(cur, 1, 0); stageA0(nxt, kt); BAR();
    mm2(1, 0);
    // ph3: publish {B0,B1,A0}(t+1)
    rdA2(cur, 1, 1); stageA1(nxt, kt); VMCNT(2); BAR();
    mm2(1, 1);
  }
  {  // tail t=31 (cur=1), no staging; entry queue {A1}=2
    rdA2(1, 0, 0); rdB2(1, 0); VMCNT(0); BAR();
    mm2(0, 0);
    rdA2(1, 0, 1); rdB2(1, 1); mm2(0, 1);
    rdA2(1, 1, 0); mm2(1, 0);
    rdA2(1, 1, 1); mm2(1, 1);
  }

#pragma unroll
  for (int i = 0; i < 8; i++) {
#pragma unroll
    for (int r = 0; r < 4; r++) {
      int mg = m0 + wr + i * 16 + ls * 4 + r;
      if (mg < count) {
        float* yp = y + (size_t)(sbase + mg) * DDIM + n0 + wn + lm;
#pragma unroll
        for (int j = 0; j < 4; j++) yp[j * 16] = acc[i][j][r];
      }
    }
  }
}

// ---------------- combine: out[t] = p0*y[s0] + p1*y[s1] ----------------
__global__ __launch_bounds__(256) void combine_kernel(const float* __restrict__ y,
                                                      const int* __restrict__ slot_of,
                                                      const float* __restrict__ prb,
                                                      float* __restrict__ out) {
  int t = blockIdx.x;
  int s0 = slot_of[t * 2], s1 = slot_of[t * 2 + 1];
  float p0 = prb[t * 2], p1 = prb[t * 2 + 1];
  float4 a = ((const float4*)(y + (size_t)s0 * DDIM))[threadIdx.x];
  float4 b = ((const float4*)(y + (size_t)s1 * DDIM))[threadIdx.x];
  float4 o;
  o.x = p0 * a.x + p1 * b.x;
  o.y = p0 * a.y + p1 * b.y;
  o.z = p0 * a.z + p1 * b.z;
  o.w = p0 * a.w + p1 * b.w;
  ((float4*)(out + (size_t)t * DDIM))[threadIdx.x] = o;
}

extern "C" void kernel_launch(void* const* d_in, const int* in_sizes, int n_in,
                              void* d_out, int out_size, void* d_ws, size_t ws_size,
                              hipStream_t stream) {
  const float* x  = (const float*)d_in[0];
  const float* wg = (const float*)d_in[1];
  const float* w1 = (const float*)d_in[2];
  const float* w3 = (const float*)d_in[3];
  const float* w2 = (const float*)d_in[4];
  float* out = (float*)d_out;
  char* ws = (char*)d_ws;

  size_t off = 0;
  int* hdr = (int*)(ws + off); off += 256;
  int* sel = (int*)(ws + off); off += (size_t)T_TOK * 2 * 4;
  float* prb = (float*)(ws + off); off += (size_t)T_TOK * 2 * 4;
  int* rows = (int*)(ws + off); off += (size_t)T_TOK * 2 * 4;
  int* slot_of = (int*)(ws + off); off += (size_t)T_TOK * 2 * 4;
  int* cnt_blk = (int*)(ws + off); off += (size_t)GBLK * 8 * 4;
  int* blk_off = (int*)(ws + off); off += (size_t)GBLK * 8 * 4;
  unsigned short* xb  = (unsigned short*)(ws + off); off += (size_t)T_TOK * DDIM * 2;
  unsigned short* w1t = (unsigned short*)(ws + off); off += (size_t)EEXP * DDIM * FDIM * 2;
  unsigned short* w3t = (unsigned short*)(ws + off); off += (size_t)EEXP * DDIM * FDIM * 2;
  unsigned short* w2t = (unsigned short*)(ws + off); off += (size_t)EEXP * DDIM * FDIM * 2;
  unsigned short* h   = (unsigned short*)(ws + off); off += (size_t)T_TOK * 2 * FDIM * 2;
  // y overlays w1t+w3t (64 MB, dead after gemm1): [T*2][D] fp32
  float* y = (float*)w1t;

  gate_kernel<<<GBLK, 256, 0, stream>>>(x, wg, xb, sel, prb, cnt_blk);
  transpose_cast3_kernel<<<dim3(32, 32, 24), 256, 0, stream>>>(w1, w3, w2, w1t, w3t, w2t);
  scan_kernel<<<1, 64, 0, stream>>>(cnt_blk, hdr, blk_off);
  build_kernel<<<T_TOK * 2 / 64, 64, 0, stream>>>(sel, blk_off, rows, slot_of);
  gemm1_kernel<<<dim3(FDIM / 128, T_TOK / 128 / 2, EEXP), 512, 0, stream>>>(xb, w1t, w3t, rows, hdr, h);
  gemm2_kernel<<<dim3(DDIM / 256, T_TOK / 128 / 2, EEXP), 512, 0, stream>>>(h, w2t, hdr, y);
  combine_kernel<<<T_TOK, 256, 0, stream>>>(y, slot_of, prb, out);
}